// Round 5
// baseline (301.437 us; speedup 1.0000x reference)
//
#include <hip/hip_runtime.h>

typedef unsigned short u16;
typedef unsigned int u32;
typedef __bf16 bf16x8 __attribute__((ext_vector_type(8)));
typedef float f32x4 __attribute__((ext_vector_type(4)));
typedef u16 u16x8 __attribute__((ext_vector_type(8)));
typedef u16 u16x2 __attribute__((ext_vector_type(2)));

__device__ __forceinline__ float bf2f(u16 u) {
    union { u32 u; float f; } c; c.u = ((u32)u) << 16; return c.f;
}
__device__ __forceinline__ u16 f2bf(float f) {
    union { float f; u32 u; } c; c.f = f;
    u32 r = c.u + 0x7fffu + ((c.u >> 16) & 1u);
    return (u16)(r >> 16);
}
__device__ __forceinline__ bf16x8 ld_frag(const u16* p) {
    return *reinterpret_cast<const bf16x8*>(p);
}

// ---------------- K0: transpose weights to [N][K] (K-contiguous), fp32 -> bf16 ----------------
__global__ __launch_bounds__(256) void k_wT(
    const float* __restrict__ qkv_w, const float* __restrict__ proj_w,
    const float* __restrict__ fc1_w, const float* __restrict__ fc2_w,
    u16* __restrict__ qkvT, u16* __restrict__ projT,
    u16* __restrict__ fc1T, u16* __restrict__ fc2T)
{
    int t = blockIdx.x * 256 + threadIdx.x;          // < 65536
    if (t < 49152) { int k = t / 384, n = t % 384; qkvT[n*128 + k] = f2bf(qkv_w[t]); }
    if (t < 16384) { int k = t / 128, n = t % 128; projT[n*128 + k] = f2bf(proj_w[t]); }
    if (t < 65536) { int k = t / 512, n = t % 512; fc1T[n*128 + k] = f2bf(fc1_w[t]); }
    if (t < 65536) { int k = t / 128, n = t % 128; fc2T[n*512 + k] = f2bf(fc2_w[t]); }
}

// ---------------- K1: LN1 + cyclic shift + window partition (fp32 in, bf16 out) ----------------
__global__ __launch_bounds__(256) void k_ln1_part(
    const float* __restrict__ x, const float* __restrict__ w, const float* __restrict__ b,
    u16* __restrict__ xw)
{
    int wv = threadIdx.x >> 6, l = threadIdx.x & 63;
    int g = blockIdx.x * 4 + wv;                      // < 100352
    int wi = g / 98, n = g % 98;
    int iw = wi & 7, ih = (wi >> 3) & 7, id = (wi >> 6) & 3, bb = wi >> 8;
    int tw = n % 7, tt = n / 7, th = tt % 7, td = tt / 7;
    int d  = (id * 2 + td + 1) & 7;
    int hh = ih * 7 + th + 3; if (hh >= 56) hh -= 56;
    int ww = iw * 7 + tw + 3; if (ww >= 56) ww -= 56;
    long src = ((((long)bb * 8 + d) * 56 + hh) * 56 + ww) * 128;
    float2 v = *(const float2*)(x + src + l * 2);
    float f0 = v.x, f1 = v.y;
    float s = f0 + f1, s2 = f0*f0 + f1*f1;
    #pragma unroll
    for (int o = 32; o; o >>= 1) { s += __shfl_xor(s, o); s2 += __shfl_xor(s2, o); }
    float mean = s * (1.f/128.f);
    float var  = s2 * (1.f/128.f) - mean*mean;
    float rstd = rsqrtf(var + 1e-5f);
    float y0 = (f0 - mean) * rstd * w[l*2]   + b[l*2];
    float y1 = (f1 - mean) * rstd * w[l*2+1] + b[l*2+1];
    u16x2 o2; o2[0] = f2bf(y0); o2[1] = f2bf(y1);
    *(u16x2*)(xw + (long)g * 128 + l * 2) = o2;
}

// ---------------- K2/K4: GEMM  C[M,N] = A[M,128] @ BT[N,128]^T + bias ----------------
__global__ __launch_bounds__(256) void k_gemm128(
    const u16* __restrict__ A, const u16* __restrict__ BT,
    const float* __restrict__ bias, u16* __restrict__ out, int ldo)
{
    __shared__ __align__(16) u16 la[128*136];
    __shared__ __align__(16) u16 lb[128*136];
    int m0 = blockIdx.x * 128, n0 = blockIdx.y * 128;
    int t = threadIdx.x;
    #pragma unroll
    for (int i = 0; i < 8; i++) {
        int u = t + i * 256;
        int r = u >> 4, c = u & 15;
        *(u16x8*)&la[r*136 + c*8] = *(const u16x8*)&A [(long)(m0 + r)*128 + c*8];
        *(u16x8*)&lb[r*136 + c*8] = *(const u16x8*)&BT[(long)(n0 + r)*128 + c*8];
    }
    __syncthreads();
    int wv = t >> 6, l = t & 63;
    int wm = (wv & 1) * 64, wn = (wv >> 1) * 64;
    int lr = l & 15, lk = (l >> 4) * 8;
    f32x4 acc[4][4] = {};
    #pragma unroll
    for (int kk = 0; kk < 4; kk++) {
        bf16x8 af[4], bfr[4];
        #pragma unroll
        for (int mi = 0; mi < 4; mi++) af[mi]  = ld_frag(&la[(wm + mi*16 + lr)*136 + kk*32 + lk]);
        #pragma unroll
        for (int ni = 0; ni < 4; ni++) bfr[ni] = ld_frag(&lb[(wn + ni*16 + lr)*136 + kk*32 + lk]);
        #pragma unroll
        for (int mi = 0; mi < 4; mi++)
            #pragma unroll
            for (int ni = 0; ni < 4; ni++)
                acc[mi][ni] = __builtin_amdgcn_mfma_f32_16x16x32_bf16(af[mi], bfr[ni], acc[mi][ni], 0, 0, 0);
    }
    int rb = (l >> 4) * 4;
    #pragma unroll
    for (int mi = 0; mi < 4; mi++)
        #pragma unroll
        for (int ni = 0; ni < 4; ni++) {
            int col = n0 + wn + ni*16 + lr;
            float bv = bias[col];
            #pragma unroll
            for (int r = 0; r < 4; r++) {
                int row = m0 + wm + mi*16 + rb + r;
                out[(long)row*ldo + col] = f2bf(acc[mi][ni][r] + bv);
            }
        }
}

// ---------------- K3: attention per (window, head) — register-resident scores ----------------
__global__ __launch_bounds__(256) void k_attn(
    const u16* __restrict__ qkv, u16* __restrict__ attn_out)
{
    __shared__ __align__(16) u16 lq[128*40];     // [row][k]  (rows >=98 zero)
    __shared__ __align__(16) u16 lk[128*40];     // [row][k]
    __shared__ __align__(16) u16 lvt[32*136];    // [ch][key] (keys >=98 zero)
    __shared__ __align__(16) u16 lp[4][16*136];  // per-wave P tile [row][key]
    int wi = blockIdx.x, h = blockIdx.y;
    int t = threadIdx.x;
    int wv = t >> 6, l = t & 63;
    const long base = (long)wi * 98 * 384 + h * 32;
    u16* lpw = lp[wv];
    // zero this wave's P buffer (cols 112..127 must stay zero for PV chunk 3)
    {
        u16x8 z8 = {};
        for (int i = l; i < 272; i += 64) *(u16x8*)&lpw[i*8] = z8;
    }
    // stage q,k (zero-padded rows)
    #pragma unroll
    for (int i = 0; i < 4; i++) {
        int u = t + i * 256;                  // < 1024
        int mat = u >> 9, row = (u >> 2) & 127, ch = u & 3;
        u16x8 v = {};
        if (row < 98) v = *(const u16x8*)&qkv[base + (long)row*384 + mat*128 + ch*8];
        u16* dst = mat ? lk : lq;
        *(u16x8*)&dst[row*40 + ch*8] = v;
    }
    // stage v transposed: lvt[ch][key], keys 98..127 zero
    #pragma unroll
    for (int i = 0; i < 2; i++) {
        int u = t + i * 256;                  // < 512
        int row = u >> 2, ch = u & 3;
        u16x8 v = {};
        if (row < 98) v = *(const u16x8*)&qkv[base + (long)row*384 + 256 + ch*8];
        #pragma unroll
        for (int j = 0; j < 8; j++) lvt[(ch*8 + j)*136 + row] = v[j];
    }
    __syncthreads();
    int lr = l & 15, lg = l >> 4, lkk = lg * 8;
    const float scale = 0.17677669529663687f;
    for (int rt = wv; rt < 7; rt += 4) {
        bf16x8 qa = ld_frag(&lq[(rt*16 + lr)*40 + lkk]);
        f32x4 s[7];
        #pragma unroll
        for (int ct = 0; ct < 7; ct++) {
            bf16x8 kb = ld_frag(&lk[(ct*16 + lr)*40 + lkk]);
            f32x4 zz = {0.f, 0.f, 0.f, 0.f};
            s[ct] = __builtin_amdgcn_mfma_f32_16x16x32_bf16(qa, kb, zz, 0, 0, 0);
        }
        #pragma unroll
        for (int ct = 0; ct < 7; ct++) {
            bool valid = (ct < 6) || (lr < 2);
            #pragma unroll
            for (int r = 0; r < 4; r++)
                s[ct][r] = valid ? s[ct][r] * scale : -1e30f;
        }
        f32x4 mx;
        #pragma unroll
        for (int r = 0; r < 4; r++) {
            float m = s[0][r];
            #pragma unroll
            for (int ct = 1; ct < 7; ct++) m = fmaxf(m, s[ct][r]);
            #pragma unroll
            for (int o = 1; o < 16; o <<= 1) m = fmaxf(m, __shfl_xor(m, o));
            mx[r] = m;
        }
        f32x4 sum = {0.f, 0.f, 0.f, 0.f};
        #pragma unroll
        for (int ct = 0; ct < 7; ct++)
            #pragma unroll
            for (int r = 0; r < 4; r++) {
                s[ct][r] = __expf(s[ct][r] - mx[r]);
                sum[r] += s[ct][r];
            }
        #pragma unroll
        for (int r = 0; r < 4; r++) {
            float ss = sum[r];
            #pragma unroll
            for (int o = 1; o < 16; o <<= 1) ss += __shfl_xor(ss, o);
            sum[r] = 1.f / ss;
        }
        #pragma unroll
        for (int ct = 0; ct < 7; ct++)
            #pragma unroll
            for (int r = 0; r < 4; r++)
                lpw[(lg*4 + r)*136 + ct*16 + lr] = f2bf(s[ct][r] * sum[r]);
        #pragma unroll
        for (int ni = 0; ni < 2; ni++) {
            f32x4 acc = {0.f, 0.f, 0.f, 0.f};
            #pragma unroll
            for (int kk = 0; kk < 4; kk++) {
                bf16x8 pa = ld_frag(&lpw[lr*136 + kk*32 + lkk]);
                bf16x8 vb = ld_frag(&lvt[(ni*16 + lr)*136 + kk*32 + lkk]);
                acc = __builtin_amdgcn_mfma_f32_16x16x32_bf16(pa, vb, acc, 0, 0, 0);
            }
            #pragma unroll
            for (int r = 0; r < 4; r++) {
                int row = rt*16 + lg*4 + r;
                if (row < 98)
                    attn_out[((long)wi*98 + row)*128 + h*32 + ni*16 + lr] = f2bf(acc[r]);
            }
        }
    }
}

// ---------------- K5: window reverse + unshift + residual + LN2 ----------------
__global__ __launch_bounds__(256) void k_res_ln2(
    const u16* __restrict__ proj_out, const float* __restrict__ x,
    const float* __restrict__ w2, const float* __restrict__ b2,
    float* __restrict__ x1, u16* __restrict__ h2out)
{
    int wv = threadIdx.x >> 6, l = threadIdx.x & 63;
    int g = blockIdx.x * 4 + wv;                 // natural token id
    int ww = g % 56; int t1 = g / 56;
    int hh = t1 % 56; int t2 = t1 / 56;
    int d = t2 & 7, bb = t2 >> 3;
    int d2 = (d + 7) & 7;
    int hs = hh - 3; if (hs < 0) hs += 56;
    int ws_ = ww - 3; if (ws_ < 0) ws_ += 56;
    int id = d2 >> 1, td = d2 & 1;
    int ih = hs / 7, th = hs % 7;
    int iw = ws_ / 7, tw = ws_ % 7;
    int wi = ((bb*4 + id)*8 + ih)*8 + iw;
    int n  = (td*7 + th)*7 + tw;
    long prow = ((long)wi*98 + n) * 128;
    long nrow = (long)g * 128;
    u16x2 pv = *(const u16x2*)&proj_out[prow + l*2];
    float2 xv = *(const float2*)&x[nrow + l*2];
    float v0 = bf2f(pv[0]) + xv.x;
    float v1 = bf2f(pv[1]) + xv.y;
    float2 o; o.x = v0; o.y = v1;
    *(float2*)&x1[nrow + l*2] = o;
    float s = v0 + v1, s2 = v0*v0 + v1*v1;
    #pragma unroll
    for (int o2 = 32; o2; o2 >>= 1) { s += __shfl_xor(s, o2); s2 += __shfl_xor(s2, o2); }
    float mean = s * (1.f/128.f), var = s2 * (1.f/128.f) - mean*mean;
    float rstd = rsqrtf(var + 1e-5f);
    float y0 = (v0 - mean)*rstd*w2[l*2]   + b2[l*2];
    float y1 = (v1 - mean)*rstd*w2[l*2+1] + b2[l*2+1];
    u16x2 oh; oh[0] = f2bf(y0); oh[1] = f2bf(y1);
    *(u16x2*)&h2out[nrow + l*2] = oh;
}

// ---------------- K6: fused MLP  out = x1 + fc2(silu(fc1(h2))) ----------------
// Wave-independent: each wave owns 32 rows; fc1 A-frags live in VGPRs; hidden
// chunk (32x64) goes through a private XOR-swizzled LDS tile; fc2 accumulates
// in registers. NO barriers. LDS 16 KB total.
__global__ __launch_bounds__(256, 3) void k_mlp(
    const u16* __restrict__ h2, const u16* __restrict__ fc1T, const float* __restrict__ b1,
    const u16* __restrict__ fc2T, const float* __restrict__ b2,
    const float* __restrict__ x1, float* __restrict__ out)
{
    __shared__ __align__(16) u16 lph[4][32*64];   // per-wave [row][64] XOR-swizzled
    int t = threadIdx.x;
    int wv = t >> 6, l = t & 63;
    int lr = l & 15, lg = l >> 4, lk = lg * 8;
    u16* lp = lph[wv];
    long rb = (long)blockIdx.x * 128 + wv * 32;   // wave's first row
    // fc1 A-fragments for own 32 rows, kept in VGPRs (64B-coalesced global reads)
    bf16x8 a[2][4];
    #pragma unroll
    for (int mt = 0; mt < 2; mt++)
        #pragma unroll
        for (int kk = 0; kk < 4; kk++)
            a[mt][kk] = ld_frag(&h2[(rb + mt*16 + lr)*128 + kk*32 + lk]);
    f32x4 oacc[2][8] = {};
    for (int ch = 0; ch < 8; ch++) {
        // phase 1: hidden[32 own rows][units ch*64..+63] -> swizzled LDS
        #pragma unroll
        for (int nt = 0; nt < 4; nt++) {
            int u = ch*64 + nt*16;
            bf16x8 bfr[4];
            #pragma unroll
            for (int kk = 0; kk < 4; kk++)
                bfr[kk] = ld_frag(&fc1T[(u + lr)*128 + kk*32 + lk]);
            float bv = b1[u + lr];
            #pragma unroll
            for (int mt = 0; mt < 2; mt++) {
                f32x4 acc = {0.f, 0.f, 0.f, 0.f};
                #pragma unroll
                for (int kk = 0; kk < 4; kk++)
                    acc = __builtin_amdgcn_mfma_f32_16x16x32_bf16(a[mt][kk], bfr[kk], acc, 0, 0, 0);
                #pragma unroll
                for (int r = 0; r < 4; r++) {
                    float v = acc[r] + bv;
                    v = v / (1.f + __expf(-v));
                    int row = mt*16 + lg*4 + r;
                    int byo = row*128 + (((nt*16 + lr)*2) ^ ((row & 7) << 4));
                    *(u16*)((char*)lp + byo) = f2bf(v);
                }
            }
        }
        // phase 2: oacc += hidden_chunk @ fc2T[:, ch*64..+63]  (same wave, no barrier)
        #pragma unroll
        for (int kk2 = 0; kk2 < 2; kk2++) {
            bf16x8 pa[2];
            #pragma unroll
            for (int mt = 0; mt < 2; mt++) {
                int row = mt*16 + lr;
                int byo = row*128 + ((kk2*64 + lg*16) ^ ((row & 7) << 4));
                pa[mt] = *(const bf16x8*)((const char*)lp + byo);
            }
            #pragma unroll
            for (int nt2 = 0; nt2 < 8; nt2++) {
                bf16x8 vb = ld_frag(&fc2T[(long)(nt2*16 + lr)*512 + ch*64 + kk2*32 + lk]);
                oacc[0][nt2] = __builtin_amdgcn_mfma_f32_16x16x32_bf16(pa[0], vb, oacc[0][nt2], 0, 0, 0);
                oacc[1][nt2] = __builtin_amdgcn_mfma_f32_16x16x32_bf16(pa[1], vb, oacc[1][nt2], 0, 0, 0);
            }
        }
    }
    // epilogue: += b2 + x1, write fp32
    #pragma unroll
    for (int nt2 = 0; nt2 < 8; nt2++) {
        int col = nt2*16 + lr;
        float bv = b2[col];
        #pragma unroll
        for (int mt = 0; mt < 2; mt++)
            #pragma unroll
            for (int r = 0; r < 4; r++) {
                long row = rb + mt*16 + lg*4 + r;
                out[row*128 + col] = oacc[mt][nt2][r] + bv + x1[row*128 + col];
            }
    }
}

extern "C" void kernel_launch(void* const* d_in, const int* in_sizes, int n_in,
                              void* d_out, int out_size, void* d_ws, size_t ws_size,
                              hipStream_t stream)
{
    const float* x      = (const float*)d_in[0];
    const float* n1w    = (const float*)d_in[1];
    const float* n1b    = (const float*)d_in[2];
    const float* qkv_w  = (const float*)d_in[3];
    const float* qkv_b  = (const float*)d_in[4];
    const float* proj_w = (const float*)d_in[5];
    const float* proj_b = (const float*)d_in[6];
    const float* n2w    = (const float*)d_in[7];
    const float* n2b    = (const float*)d_in[8];
    const float* fc1_w  = (const float*)d_in[9];
    const float* fc1_b  = (const float*)d_in[10];
    const float* fc2_w  = (const float*)d_in[11];
    const float* fc2_b  = (const float*)d_in[12];
    float* out = (float*)d_out;

    u16* ws16  = (u16*)d_ws;
    u16* xw    = ws16;                        // 12,845,056 u16 (later: attn_out, then h2)
    u16* qkv   = xw + 12845056;               // 38,535,168 u16 (later: proj_out)
    u16* qkvT  = qkv + 38535168;              // 49,152
    u16* projT = qkvT + 49152;                // 16,384
    u16* fc1T  = projT + 16384;               // 65,536
    u16* fc2T  = fc1T + 65536;                // 65,536

    k_wT<<<256, 256, 0, stream>>>(qkv_w, proj_w, fc1_w, fc2_w, qkvT, projT, fc1T, fc2T);
    k_ln1_part<<<25088, 256, 0, stream>>>(x, n1w, n1b, xw);
    dim3 gq(784, 3);
    k_gemm128<<<gq, 256, 0, stream>>>(xw, qkvT, qkv_b, qkv, 384);
    dim3 ga(1024, 4);
    k_attn<<<ga, 256, 0, stream>>>(qkv, xw);                        // attn_out -> xw region
    dim3 gp(784, 1);
    k_gemm128<<<gp, 256, 0, stream>>>(xw, projT, proj_b, qkv, 128); // proj_out -> qkv region
    k_res_ln2<<<25088, 256, 0, stream>>>(qkv, x, n2w, n2b, out /*x1 fp32*/, xw /*h2 bf16*/);
    k_mlp<<<784, 256, 0, stream>>>(xw /*h2*/, fc1T, fc1_b, fc2T, fc2_b, out /*x1*/, out);
}

// Round 7
// 253.289 us; speedup vs baseline: 1.1901x; 1.1901x over previous
//
#include <hip/hip_runtime.h>

typedef unsigned short u16;
typedef unsigned int u32;
typedef __bf16 bf16x8 __attribute__((ext_vector_type(8)));
typedef float f32x4 __attribute__((ext_vector_type(4)));
typedef u16 u16x8 __attribute__((ext_vector_type(8)));
typedef u16 u16x2 __attribute__((ext_vector_type(2)));

__device__ __forceinline__ float bf2f(u16 u) {
    union { u32 u; float f; } c; c.u = ((u32)u) << 16; return c.f;
}
__device__ __forceinline__ u16 f2bf(float f) {
    union { float f; u32 u; } c; c.f = f;
    u32 r = c.u + 0x7fffu + ((c.u >> 16) & 1u);
    return (u16)(r >> 16);
}
__device__ __forceinline__ bf16x8 ld_frag(const u16* p) {
    return *reinterpret_cast<const bf16x8*>(p);
}

// ---------------- K0: transpose weights to [N][K] (K-contiguous), fp32 -> bf16 ----------------
__global__ __launch_bounds__(256) void k_wT(
    const float* __restrict__ qkv_w, const float* __restrict__ proj_w,
    const float* __restrict__ fc1_w, const float* __restrict__ fc2_w,
    u16* __restrict__ qkvT, u16* __restrict__ projT,
    u16* __restrict__ fc1T, u16* __restrict__ fc2T)
{
    int t = blockIdx.x * 256 + threadIdx.x;          // < 65536
    if (t < 49152) { int k = t / 384, n = t % 384; qkvT[n*128 + k] = f2bf(qkv_w[t]); }
    if (t < 16384) { int k = t / 128, n = t % 128; projT[n*128 + k] = f2bf(proj_w[t]); }
    if (t < 65536) { int k = t / 512, n = t % 512; fc1T[n*128 + k] = f2bf(fc1_w[t]); }
    if (t < 65536) { int k = t / 128, n = t % 128; fc2T[n*512 + k] = f2bf(fc2_w[t]); }
}

// ---------------- K1: LN1 + cyclic shift + window partition (fp32 in, bf16 out) ----------------
__global__ __launch_bounds__(256) void k_ln1_part(
    const float* __restrict__ x, const float* __restrict__ w, const float* __restrict__ b,
    u16* __restrict__ xw)
{
    int wv = threadIdx.x >> 6, l = threadIdx.x & 63;
    int g = blockIdx.x * 4 + wv;                      // < 100352
    int wi = g / 98, n = g % 98;
    int iw = wi & 7, ih = (wi >> 3) & 7, id = (wi >> 6) & 3, bb = wi >> 8;
    int tw = n % 7, tt = n / 7, th = tt % 7, td = tt / 7;
    int d  = (id * 2 + td + 1) & 7;
    int hh = ih * 7 + th + 3; if (hh >= 56) hh -= 56;
    int ww = iw * 7 + tw + 3; if (ww >= 56) ww -= 56;
    long src = ((((long)bb * 8 + d) * 56 + hh) * 56 + ww) * 128;
    float2 v = *(const float2*)(x + src + l * 2);
    float f0 = v.x, f1 = v.y;
    float s = f0 + f1, s2 = f0*f0 + f1*f1;
    #pragma unroll
    for (int o = 32; o; o >>= 1) { s += __shfl_xor(s, o); s2 += __shfl_xor(s2, o); }
    float mean = s * (1.f/128.f);
    float var  = s2 * (1.f/128.f) - mean*mean;
    float rstd = rsqrtf(var + 1e-5f);
    float y0 = (f0 - mean) * rstd * w[l*2]   + b[l*2];
    float y1 = (f1 - mean) * rstd * w[l*2+1] + b[l*2+1];
    u16x2 o2; o2[0] = f2bf(y0); o2[1] = f2bf(y1);
    *(u16x2*)(xw + (long)g * 128 + l * 2) = o2;
}

// ---------------- K4: GEMM  C[M,N] = A[M,128] @ BT[N,128]^T + bias (proj) ----------------
__global__ __launch_bounds__(256) void k_gemm128(
    const u16* __restrict__ A, const u16* __restrict__ BT,
    const float* __restrict__ bias, u16* __restrict__ out, int ldo)
{
    __shared__ __align__(16) u16 la[128*136];
    __shared__ __align__(16) u16 lb[128*136];
    int m0 = blockIdx.x * 128, n0 = blockIdx.y * 128;
    int t = threadIdx.x;
    #pragma unroll
    for (int i = 0; i < 8; i++) {
        int u = t + i * 256;
        int r = u >> 4, c = u & 15;
        *(u16x8*)&la[r*136 + c*8] = *(const u16x8*)&A [(long)(m0 + r)*128 + c*8];
        *(u16x8*)&lb[r*136 + c*8] = *(const u16x8*)&BT[(long)(n0 + r)*128 + c*8];
    }
    __syncthreads();
    int wv = t >> 6, l = t & 63;
    int wm = (wv & 1) * 64, wn = (wv >> 1) * 64;
    int lr = l & 15, lk = (l >> 4) * 8;
    f32x4 acc[4][4] = {};
    #pragma unroll
    for (int kk = 0; kk < 4; kk++) {
        bf16x8 af[4], bfr[4];
        #pragma unroll
        for (int mi = 0; mi < 4; mi++) af[mi]  = ld_frag(&la[(wm + mi*16 + lr)*136 + kk*32 + lk]);
        #pragma unroll
        for (int ni = 0; ni < 4; ni++) bfr[ni] = ld_frag(&lb[(wn + ni*16 + lr)*136 + kk*32 + lk]);
        #pragma unroll
        for (int mi = 0; mi < 4; mi++)
            #pragma unroll
            for (int ni = 0; ni < 4; ni++)
                acc[mi][ni] = __builtin_amdgcn_mfma_f32_16x16x32_bf16(af[mi], bfr[ni], acc[mi][ni], 0, 0, 0);
    }
    int rb = (l >> 4) * 4;
    #pragma unroll
    for (int mi = 0; mi < 4; mi++)
        #pragma unroll
        for (int ni = 0; ni < 4; ni++) {
            int col = n0 + wn + ni*16 + lr;
            float bv = bias[col];
            #pragma unroll
            for (int r = 0; r < 4; r++) {
                int row = m0 + wm + mi*16 + rb + r;
                out[(long)row*ldo + col] = f2bf(acc[mi][ni][r] + bv);
            }
        }
}

// ---------------- K3: fused QKV + attention, one block per window ----------------
// Stages the window's 98x128 input once; per head computes q/k/v via MFMA from
// LDS + L2-hot qkvT, then runs register-resident-score attention (r3 scheme).
// Writes attn_out in place over xw (block-disjoint rows, staged before write).
__global__ __launch_bounds__(256) void k_attn(
    const u16* xw, const u16* __restrict__ qkvT,
    const float* __restrict__ qkv_b, u16* attn_out)
{
    __shared__ __align__(16) u16 lxw[112*136];   // window input rows (98 real + 14 zero)
    __shared__ __align__(16) u16 lq[112*40];     // [row][k] per head
    __shared__ __align__(16) u16 lk[112*40];     // [row][k] per head
    __shared__ __align__(16) u16 lvt[32*136];    // [ch][key] per head
    __shared__ __align__(16) u16 lp[4][16*136];  // per-wave P tile [row][key]
    int wi = blockIdx.x;
    int t = threadIdx.x;
    int wv = t >> 6, l = t & 63;
    int lr = l & 15, lg = l >> 4, lkk = lg * 8;
    u16* lpw = lp[wv];
    u16x8 z8 = {};
    // zero this wave's P buffer (cols 112..127 must stay zero for PV chunk 3)
    for (int i = l; i < 272; i += 64) *(u16x8*)&lpw[i*8] = z8;
    // zero lvt: QKV phase writes only keys 0..111; PV reads keys up to 127.
    // Uninitialized LDS at keys 112..127 was the round-6 NaN (0 x NaN = NaN in MFMA).
    for (int i = t; i < 544; i += 256) *(u16x8*)&lvt[i*8] = z8;
    // stage window rows
    for (int u = t; u < 112*16; u += 256) {
        int row = u >> 4, c = u & 15;
        u16x8 v = z8;
        if (row < 98) v = *(const u16x8*)&xw[((long)wi*98 + row)*128 + c*8];
        *(u16x8*)&lxw[row*136 + c*8] = v;
    }
    __syncthreads();
    const float scale = 0.17677669529663687f;
    for (int h = 0; h < 4; h++) {
        // ---- QKV for this head: 42 jobs = {q,k,v} x 7 row-tiles x 2 ch-tiles ----
        for (int job = wv; job < 42; job += 4) {
            int mat = job / 14, rem = job % 14, mt = rem >> 1, nt = rem & 1;
            int ch = mat*128 + h*32 + nt*16 + lr;          // qkvT row (output channel)
            bf16x8 bfr[4];
            #pragma unroll
            for (int kk = 0; kk < 4; kk++)
                bfr[kk] = ld_frag(&qkvT[(long)ch*128 + kk*32 + lkk]);
            f32x4 acc = {0.f, 0.f, 0.f, 0.f};
            #pragma unroll
            for (int kk = 0; kk < 4; kk++) {
                bf16x8 a = ld_frag(&lxw[(mt*16 + lr)*136 + kk*32 + lkk]);
                acc = __builtin_amdgcn_mfma_f32_16x16x32_bf16(a, bfr[kk], acc, 0, 0, 0);
            }
            float bv = qkv_b[ch];
            #pragma unroll
            for (int r = 0; r < 4; r++) {
                int row = mt*16 + lg*4 + r;
                u16 val = f2bf(acc[r] + bv);
                if (mat == 0)      lq[row*40 + nt*16 + lr] = val;
                else if (mat == 1) lk[row*40 + nt*16 + lr] = val;
                else               lvt[(nt*16 + lr)*136 + row] = val;
            }
        }
        __syncthreads();
        // ---- attention: scores in VGPRs, 16-lane softmax, P via per-wave LDS ----
        for (int rt = wv; rt < 7; rt += 4) {
            bf16x8 qa = ld_frag(&lq[(rt*16 + lr)*40 + lkk]);
            f32x4 s[7];
            #pragma unroll
            for (int ct = 0; ct < 7; ct++) {
                bf16x8 kb = ld_frag(&lk[(ct*16 + lr)*40 + lkk]);
                f32x4 zz = {0.f, 0.f, 0.f, 0.f};
                s[ct] = __builtin_amdgcn_mfma_f32_16x16x32_bf16(qa, kb, zz, 0, 0, 0);
            }
            #pragma unroll
            for (int ct = 0; ct < 7; ct++) {
                bool valid = (ct < 6) || (lr < 2);
                #pragma unroll
                for (int r = 0; r < 4; r++)
                    s[ct][r] = valid ? s[ct][r] * scale : -1e30f;
            }
            f32x4 mx;
            #pragma unroll
            for (int r = 0; r < 4; r++) {
                float m = s[0][r];
                #pragma unroll
                for (int ct = 1; ct < 7; ct++) m = fmaxf(m, s[ct][r]);
                #pragma unroll
                for (int o = 1; o < 16; o <<= 1) m = fmaxf(m, __shfl_xor(m, o));
                mx[r] = m;
            }
            f32x4 sum = {0.f, 0.f, 0.f, 0.f};
            #pragma unroll
            for (int ct = 0; ct < 7; ct++)
                #pragma unroll
                for (int r = 0; r < 4; r++) {
                    s[ct][r] = __expf(s[ct][r] - mx[r]);
                    sum[r] += s[ct][r];
                }
            #pragma unroll
            for (int r = 0; r < 4; r++) {
                float ss = sum[r];
                #pragma unroll
                for (int o = 1; o < 16; o <<= 1) ss += __shfl_xor(ss, o);
                sum[r] = 1.f / ss;
            }
            #pragma unroll
            for (int ct = 0; ct < 7; ct++)
                #pragma unroll
                for (int r = 0; r < 4; r++)
                    lpw[(lg*4 + r)*136 + ct*16 + lr] = f2bf(s[ct][r] * sum[r]);
            #pragma unroll
            for (int ni = 0; ni < 2; ni++) {
                f32x4 acc = {0.f, 0.f, 0.f, 0.f};
                #pragma unroll
                for (int kk = 0; kk < 4; kk++) {
                    bf16x8 pa = ld_frag(&lpw[lr*136 + kk*32 + lkk]);
                    bf16x8 vb = ld_frag(&lvt[(ni*16 + lr)*136 + kk*32 + lkk]);
                    acc = __builtin_amdgcn_mfma_f32_16x16x32_bf16(pa, vb, acc, 0, 0, 0);
                }
                #pragma unroll
                for (int r = 0; r < 4; r++) {
                    int row = rt*16 + lg*4 + r;
                    if (row < 98)
                        attn_out[((long)wi*98 + row)*128 + h*32 + ni*16 + lr] = f2bf(acc[r]);
                }
            }
        }
        __syncthreads();   // protect lq/lk/lvt before next head overwrites
    }
}

// ---------------- K5: window reverse + unshift + residual + LN2 ----------------
__global__ __launch_bounds__(256) void k_res_ln2(
    const u16* __restrict__ proj_out, const float* __restrict__ x,
    const float* __restrict__ w2, const float* __restrict__ b2,
    float* __restrict__ x1, u16* __restrict__ h2out)
{
    int wv = threadIdx.x >> 6, l = threadIdx.x & 63;
    int g = blockIdx.x * 4 + wv;                 // natural token id
    int ww = g % 56; int t1 = g / 56;
    int hh = t1 % 56; int t2 = t1 / 56;
    int d = t2 & 7, bb = t2 >> 3;
    int d2 = (d + 7) & 7;
    int hs = hh - 3; if (hs < 0) hs += 56;
    int ws_ = ww - 3; if (ws_ < 0) ws_ += 56;
    int id = d2 >> 1, td = d2 & 1;
    int ih = hs / 7, th = hs % 7;
    int iw = ws_ / 7, tw = ws_ % 7;
    int wi = ((bb*4 + id)*8 + ih)*8 + iw;
    int n  = (td*7 + th)*7 + tw;
    long prow = ((long)wi*98 + n) * 128;
    long nrow = (long)g * 128;
    u16x2 pv = *(const u16x2*)&proj_out[prow + l*2];
    float2 xv = *(const float2*)&x[nrow + l*2];
    float v0 = bf2f(pv[0]) + xv.x;
    float v1 = bf2f(pv[1]) + xv.y;
    float2 o; o.x = v0; o.y = v1;
    *(float2*)&x1[nrow + l*2] = o;
    float s = v0 + v1, s2 = v0*v0 + v1*v1;
    #pragma unroll
    for (int o2 = 32; o2; o2 >>= 1) { s += __shfl_xor(s, o2); s2 += __shfl_xor(s2, o2); }
    float mean = s * (1.f/128.f), var = s2 * (1.f/128.f) - mean*mean;
    float rstd = rsqrtf(var + 1e-5f);
    float y0 = (v0 - mean)*rstd*w2[l*2]   + b2[l*2];
    float y1 = (v1 - mean)*rstd*w2[l*2+1] + b2[l*2+1];
    u16x2 oh; oh[0] = f2bf(y0); oh[1] = f2bf(y1);
    *(u16x2*)&h2out[nrow + l*2] = oh;
}

// ---------------- K6: fused MLP  out = x1 + fc2(silu(fc1(h2))) ----------------
// Hidden dim processed in 8 chunks of 64 units; double-buffered 64x72 chunk LDS.
// Output accumulators register-resident. LDS 35.8 KB -> 4 blocks/CU. (r4 version)
__global__ __launch_bounds__(256, 4) void k_mlp(
    const u16* __restrict__ h2, const u16* __restrict__ fc1T, const float* __restrict__ b1,
    const u16* __restrict__ fc2T, const float* __restrict__ b2,
    const float* __restrict__ x1, float* __restrict__ out)
{
    __shared__ __align__(16) u16 lh[64*136];       // input tile [64][128+pad]
    __shared__ __align__(16) u16 lhc[2][64*72];    // hidden chunk, double-buffered
    int m0 = blockIdx.x * 64;
    int t = threadIdx.x;
    int wv = t >> 6, l = t & 63;
    int lr = l & 15, lg = l >> 4, lk = lg * 8;
    #pragma unroll
    for (int i = 0; i < 4; i++) {
        int u = t + i * 256;                 // < 1024
        int r = u >> 4, c = u & 15;
        *(u16x8*)&lh[r*136 + c*8] = *(const u16x8*)&h2[(long)(m0 + r)*128 + c*8];
    }
    __syncthreads();
    f32x4 oacc[4][2] = {};                   // out cols wv*32 + nt*16 + lr
    for (int ch = 0; ch < 8; ch++) {
        u16* lc = lhc[ch & 1];
        int un0 = ch*64 + wv*16;
        bf16x8 bfr[4];
        #pragma unroll
        for (int kk = 0; kk < 4; kk++)
            bfr[kk] = ld_frag(&fc1T[(un0 + lr)*128 + kk*32 + lk]);
        float bv = b1[un0 + lr];
        #pragma unroll
        for (int mt = 0; mt < 4; mt++) {
            f32x4 acc = {0.f, 0.f, 0.f, 0.f};
            #pragma unroll
            for (int kk = 0; kk < 4; kk++) {
                bf16x8 a = ld_frag(&lh[(mt*16 + lr)*136 + kk*32 + lk]);
                acc = __builtin_amdgcn_mfma_f32_16x16x32_bf16(a, bfr[kk], acc, 0, 0, 0);
            }
            #pragma unroll
            for (int r = 0; r < 4; r++) {
                float v = acc[r] + bv;
                v = v / (1.f + __expf(-v));
                lc[(mt*16 + lg*4 + r)*72 + wv*16 + lr] = f2bf(v);
            }
        }
        __syncthreads();                     // chunk ready; also protects buf reuse
        #pragma unroll
        for (int nt = 0; nt < 2; nt++) {
            int col = wv*32 + nt*16 + lr;
            bf16x8 b0 = ld_frag(&fc2T[(long)col*512 + ch*64 + lk]);
            bf16x8 b1f = ld_frag(&fc2T[(long)col*512 + ch*64 + 32 + lk]);
            #pragma unroll
            for (int mt = 0; mt < 4; mt++) {
                bf16x8 a0 = ld_frag(&lc[(mt*16 + lr)*72 + lk]);
                bf16x8 a1 = ld_frag(&lc[(mt*16 + lr)*72 + 32 + lk]);
                oacc[mt][nt] = __builtin_amdgcn_mfma_f32_16x16x32_bf16(a0, b0, oacc[mt][nt], 0, 0, 0);
                oacc[mt][nt] = __builtin_amdgcn_mfma_f32_16x16x32_bf16(a1, b1f, oacc[mt][nt], 0, 0, 0);
            }
        }
    }
    #pragma unroll
    for (int nt = 0; nt < 2; nt++) {
        int col = wv*32 + nt*16 + lr;
        float bv = b2[col];
        #pragma unroll
        for (int mt = 0; mt < 4; mt++) {
            #pragma unroll
            for (int r = 0; r < 4; r++) {
                int row = m0 + mt*16 + lg*4 + r;
                out[(long)row*128 + col] = oacc[mt][nt][r] + bv + x1[(long)row*128 + col];
            }
        }
    }
}

extern "C" void kernel_launch(void* const* d_in, const int* in_sizes, int n_in,
                              void* d_out, int out_size, void* d_ws, size_t ws_size,
                              hipStream_t stream)
{
    const float* x      = (const float*)d_in[0];
    const float* n1w    = (const float*)d_in[1];
    const float* n1b    = (const float*)d_in[2];
    const float* qkv_w  = (const float*)d_in[3];
    const float* qkv_b  = (const float*)d_in[4];
    const float* proj_w = (const float*)d_in[5];
    const float* proj_b = (const float*)d_in[6];
    const float* n2w    = (const float*)d_in[7];
    const float* n2b    = (const float*)d_in[8];
    const float* fc1_w  = (const float*)d_in[9];
    const float* fc1_b  = (const float*)d_in[10];
    const float* fc2_w  = (const float*)d_in[11];
    const float* fc2_b  = (const float*)d_in[12];
    float* out = (float*)d_out;

    u16* ws16  = (u16*)d_ws;
    u16* xw    = ws16;                        // 12,845,056 u16 (xw -> attn_out in place -> h2)
    u16* pout  = xw + 12845056;               // proj_out region (12.8M u16 used)
    u16* qkvT  = pout + 38535168;             // 49,152
    u16* projT = qkvT + 49152;                // 16,384
    u16* fc1T  = projT + 16384;               // 65,536
    u16* fc2T  = fc1T + 65536;                // 65,536

    k_wT<<<256, 256, 0, stream>>>(qkv_w, proj_w, fc1_w, fc2_w, qkvT, projT, fc1T, fc2T);
    k_ln1_part<<<25088, 256, 0, stream>>>(x, n1w, n1b, xw);
    k_attn<<<1024, 256, 0, stream>>>(xw, qkvT, qkv_b, xw);          // qkv fused; in-place out
    dim3 gp(784, 1);
    k_gemm128<<<gp, 256, 0, stream>>>(xw, projT, proj_b, pout, 128); // proj_out
    k_res_ln2<<<25088, 256, 0, stream>>>(pout, x, n2w, n2b, out /*x1 fp32*/, xw /*h2 bf16*/);
    k_mlp<<<1568, 256, 0, stream>>>(xw /*h2*/, fc1T, fc1_b, fc2T, fc2_b, out /*x1*/, out);
}

// Round 8
// 218.958 us; speedup vs baseline: 1.3767x; 1.1568x over previous
//
#include <hip/hip_runtime.h>

typedef unsigned short u16;
typedef unsigned int u32;
typedef __bf16 bf16x8 __attribute__((ext_vector_type(8)));
typedef float f32x4 __attribute__((ext_vector_type(4)));
typedef u16 u16x8 __attribute__((ext_vector_type(8)));
typedef u16 u16x2 __attribute__((ext_vector_type(2)));

__device__ __forceinline__ float bf2f(u16 u) {
    union { u32 u; float f; } c; c.u = ((u32)u) << 16; return c.f;
}
__device__ __forceinline__ u16 f2bf(float f) {
    union { float f; u32 u; } c; c.f = f;
    u32 r = c.u + 0x7fffu + ((c.u >> 16) & 1u);
    return (u16)(r >> 16);
}
__device__ __forceinline__ bf16x8 ld_frag(const u16* p) {
    return *reinterpret_cast<const bf16x8*>(p);
}

// ---------------- K0: transpose weights to [N][K] (K-contiguous), fp32 -> bf16 ----------------
__global__ __launch_bounds__(256) void k_wT(
    const float* __restrict__ qkv_w, const float* __restrict__ proj_w,
    const float* __restrict__ fc1_w, const float* __restrict__ fc2_w,
    u16* __restrict__ qkvT, u16* __restrict__ projT,
    u16* __restrict__ fc1T, u16* __restrict__ fc2T)
{
    int t = blockIdx.x * 256 + threadIdx.x;          // < 65536
    if (t < 49152) { int k = t / 384, n = t % 384; qkvT[n*128 + k] = f2bf(qkv_w[t]); }
    if (t < 16384) { int k = t / 128, n = t % 128; projT[n*128 + k] = f2bf(proj_w[t]); }
    if (t < 65536) { int k = t / 512, n = t % 512; fc1T[n*128 + k] = f2bf(fc1_w[t]); }
    if (t < 65536) { int k = t / 128, n = t % 128; fc2T[n*512 + k] = f2bf(fc2_w[t]); }
}

// ---------------- K1: LN1 + cyclic shift + window partition (fp32 in, bf16 out) ----------------
__global__ __launch_bounds__(256) void k_ln1_part(
    const float* __restrict__ x, const float* __restrict__ w, const float* __restrict__ b,
    u16* __restrict__ xw)
{
    int wv = threadIdx.x >> 6, l = threadIdx.x & 63;
    int g = blockIdx.x * 4 + wv;                      // < 100352
    int wi = g / 98, n = g % 98;
    int iw = wi & 7, ih = (wi >> 3) & 7, id = (wi >> 6) & 3, bb = wi >> 8;
    int tw = n % 7, tt = n / 7, th = tt % 7, td = tt / 7;
    int d  = (id * 2 + td + 1) & 7;
    int hh = ih * 7 + th + 3; if (hh >= 56) hh -= 56;
    int ww = iw * 7 + tw + 3; if (ww >= 56) ww -= 56;
    long src = ((((long)bb * 8 + d) * 56 + hh) * 56 + ww) * 128;
    float2 v = *(const float2*)(x + src + l * 2);
    float f0 = v.x, f1 = v.y;
    float s = f0 + f1, s2 = f0*f0 + f1*f1;
    #pragma unroll
    for (int o = 32; o; o >>= 1) { s += __shfl_xor(s, o); s2 += __shfl_xor(s2, o); }
    float mean = s * (1.f/128.f);
    float var  = s2 * (1.f/128.f) - mean*mean;
    float rstd = rsqrtf(var + 1e-5f);
    float y0 = (f0 - mean) * rstd * w[l*2]   + b[l*2];
    float y1 = (f1 - mean) * rstd * w[l*2+1] + b[l*2+1];
    u16x2 o2; o2[0] = f2bf(y0); o2[1] = f2bf(y1);
    *(u16x2*)(xw + (long)g * 128 + l * 2) = o2;
}

// ---------------- K2/K4: GEMM  C[M,N] = A[M,128] @ BT[N,128]^T + bias ----------------
__global__ __launch_bounds__(256) void k_gemm128(
    const u16* __restrict__ A, const u16* __restrict__ BT,
    const float* __restrict__ bias, u16* __restrict__ out, int ldo)
{
    __shared__ __align__(16) u16 la[128*136];
    __shared__ __align__(16) u16 lb[128*136];
    int m0 = blockIdx.x * 128, n0 = blockIdx.y * 128;
    int t = threadIdx.x;
    #pragma unroll
    for (int i = 0; i < 8; i++) {
        int u = t + i * 256;
        int r = u >> 4, c = u & 15;
        *(u16x8*)&la[r*136 + c*8] = *(const u16x8*)&A [(long)(m0 + r)*128 + c*8];
        *(u16x8*)&lb[r*136 + c*8] = *(const u16x8*)&BT[(long)(n0 + r)*128 + c*8];
    }
    __syncthreads();
    int wv = t >> 6, l = t & 63;
    int wm = (wv & 1) * 64, wn = (wv >> 1) * 64;
    int lr = l & 15, lk = (l >> 4) * 8;
    f32x4 acc[4][4] = {};
    #pragma unroll
    for (int kk = 0; kk < 4; kk++) {
        bf16x8 af[4], bfr[4];
        #pragma unroll
        for (int mi = 0; mi < 4; mi++) af[mi]  = ld_frag(&la[(wm + mi*16 + lr)*136 + kk*32 + lk]);
        #pragma unroll
        for (int ni = 0; ni < 4; ni++) bfr[ni] = ld_frag(&lb[(wn + ni*16 + lr)*136 + kk*32 + lk]);
        #pragma unroll
        for (int mi = 0; mi < 4; mi++)
            #pragma unroll
            for (int ni = 0; ni < 4; ni++)
                acc[mi][ni] = __builtin_amdgcn_mfma_f32_16x16x32_bf16(af[mi], bfr[ni], acc[mi][ni], 0, 0, 0);
    }
    int rb = (l >> 4) * 4;
    #pragma unroll
    for (int mi = 0; mi < 4; mi++)
        #pragma unroll
        for (int ni = 0; ni < 4; ni++) {
            int col = n0 + wn + ni*16 + lr;
            float bv = bias[col];
            #pragma unroll
            for (int r = 0; r < 4; r++) {
                int row = m0 + wm + mi*16 + rb + r;
                out[(long)row*ldo + col] = f2bf(acc[mi][ni][r] + bv);
            }
        }
}

// ---------------- K3: attention per (window, head) — register-resident scores (r3) ----------------
__global__ __launch_bounds__(256) void k_attn(
    const u16* __restrict__ qkv, u16* __restrict__ attn_out)
{
    __shared__ __align__(16) u16 lq[128*40];     // [row][k]  (rows >=98 zero)
    __shared__ __align__(16) u16 lk[128*40];     // [row][k]
    __shared__ __align__(16) u16 lvt[32*136];    // [ch][key] (keys >=98 zero)
    __shared__ __align__(16) u16 lp[4][16*136];  // per-wave P tile [row][key]
    int wi = blockIdx.x, h = blockIdx.y;
    int t = threadIdx.x;
    int wv = t >> 6, l = t & 63;
    const long base = (long)wi * 98 * 384 + h * 32;
    u16* lpw = lp[wv];
    // zero this wave's P buffer (cols 112..127 must stay zero for PV chunk 3)
    {
        u16x8 z8 = {};
        for (int i = l; i < 272; i += 64) *(u16x8*)&lpw[i*8] = z8;
    }
    // stage q,k (zero-padded rows)
    #pragma unroll
    for (int i = 0; i < 4; i++) {
        int u = t + i * 256;                  // < 1024
        int mat = u >> 9, row = (u >> 2) & 127, ch = u & 3;
        u16x8 v = {};
        if (row < 98) v = *(const u16x8*)&qkv[base + (long)row*384 + mat*128 + ch*8];
        u16* dst = mat ? lk : lq;
        *(u16x8*)&dst[row*40 + ch*8] = v;
    }
    // stage v transposed: lvt[ch][key], keys 98..127 zero
    #pragma unroll
    for (int i = 0; i < 2; i++) {
        int u = t + i * 256;                  // < 512
        int row = u >> 2, ch = u & 3;
        u16x8 v = {};
        if (row < 98) v = *(const u16x8*)&qkv[base + (long)row*384 + 256 + ch*8];
        #pragma unroll
        for (int j = 0; j < 8; j++) lvt[(ch*8 + j)*136 + row] = v[j];
    }
    __syncthreads();
    int lr = l & 15, lg = l >> 4, lkk = lg * 8;
    const float scale = 0.17677669529663687f;
    for (int rt = wv; rt < 7; rt += 4) {
        bf16x8 qa = ld_frag(&lq[(rt*16 + lr)*40 + lkk]);
        f32x4 s[7];
        #pragma unroll
        for (int ct = 0; ct < 7; ct++) {
            bf16x8 kb = ld_frag(&lk[(ct*16 + lr)*40 + lkk]);
            f32x4 zz = {0.f, 0.f, 0.f, 0.f};
            s[ct] = __builtin_amdgcn_mfma_f32_16x16x32_bf16(qa, kb, zz, 0, 0, 0);
        }
        #pragma unroll
        for (int ct = 0; ct < 7; ct++) {
            bool valid = (ct < 6) || (lr < 2);
            #pragma unroll
            for (int r = 0; r < 4; r++)
                s[ct][r] = valid ? s[ct][r] * scale : -1e30f;
        }
        f32x4 mx;
        #pragma unroll
        for (int r = 0; r < 4; r++) {
            float m = s[0][r];
            #pragma unroll
            for (int ct = 1; ct < 7; ct++) m = fmaxf(m, s[ct][r]);
            #pragma unroll
            for (int o = 1; o < 16; o <<= 1) m = fmaxf(m, __shfl_xor(m, o));
            mx[r] = m;
        }
        f32x4 sum = {0.f, 0.f, 0.f, 0.f};
        #pragma unroll
        for (int ct = 0; ct < 7; ct++)
            #pragma unroll
            for (int r = 0; r < 4; r++) {
                s[ct][r] = __expf(s[ct][r] - mx[r]);
                sum[r] += s[ct][r];
            }
        #pragma unroll
        for (int r = 0; r < 4; r++) {
            float ss = sum[r];
            #pragma unroll
            for (int o = 1; o < 16; o <<= 1) ss += __shfl_xor(ss, o);
            sum[r] = 1.f / ss;
        }
        #pragma unroll
        for (int ct = 0; ct < 7; ct++)
            #pragma unroll
            for (int r = 0; r < 4; r++)
                lpw[(lg*4 + r)*136 + ct*16 + lr] = f2bf(s[ct][r] * sum[r]);
        #pragma unroll
        for (int ni = 0; ni < 2; ni++) {
            f32x4 acc = {0.f, 0.f, 0.f, 0.f};
            #pragma unroll
            for (int kk = 0; kk < 4; kk++) {
                bf16x8 pa = ld_frag(&lpw[lr*136 + kk*32 + lkk]);
                bf16x8 vb = ld_frag(&lvt[(ni*16 + lr)*136 + kk*32 + lkk]);
                acc = __builtin_amdgcn_mfma_f32_16x16x32_bf16(pa, vb, acc, 0, 0, 0);
            }
            #pragma unroll
            for (int r = 0; r < 4; r++) {
                int row = rt*16 + lg*4 + r;
                if (row < 98)
                    attn_out[((long)wi*98 + row)*128 + h*32 + ni*16 + lr] = f2bf(acc[r]);
            }
        }
    }
}

// ---------------- K6: fused res+LN2+MLP: out = x1 + fc2(silu(fc1(LN2(x1)))),
//                  x1 = window_reverse(proj_out) + x.  (r4 mlp body; res_ln2 fused in)
// LDS: lx1 17.4K + lh 17.4K + lhc 18.4K = 53.2 KB -> 3 blocks/CU.
__global__ __launch_bounds__(256, 3) void k_mlp2(
    const u16* __restrict__ pout, const float* __restrict__ x,
    const float* __restrict__ w2, const float* __restrict__ b2n,
    const u16* __restrict__ fc1T, const float* __restrict__ b1,
    const u16* __restrict__ fc2T, const float* __restrict__ b2,
    float* __restrict__ out)
{
    __shared__ __align__(16) u16 lx1[64*136];      // x1 (bf16) for epilogue
    __shared__ __align__(16) u16 lh [64*136];      // h2 = LN2(x1) (bf16)
    __shared__ __align__(16) u16 lhc[2][64*72];    // hidden chunk, double-buffered
    int m0 = blockIdx.x * 64;
    int t = threadIdx.x;
    int wv = t >> 6, l = t & 63;
    int lr = l & 15, lg = l >> 4, lk = lg * 8;
    // ---- staging: 16 rows per wave: gather + residual + LN2 ----
    for (int rr = 0; rr < 16; rr++) {
        int row = wv*16 + rr;
        int g = m0 + row;                       // natural token id
        int ww = g % 56; int t1 = g / 56;
        int hh = t1 % 56; int t2 = t1 / 56;
        int d = t2 & 7, bb = t2 >> 3;
        int d2 = (d + 7) & 7;
        int hs = hh - 3; if (hs < 0) hs += 56;
        int ws_ = ww - 3; if (ws_ < 0) ws_ += 56;
        int id = d2 >> 1, td = d2 & 1;
        int ih = hs / 7, th = hs % 7;
        int iw = ws_ / 7, tw = ws_ % 7;
        int wi = ((bb*4 + id)*8 + ih)*8 + iw;
        int n  = (td*7 + th)*7 + tw;
        long prow = ((long)wi*98 + n) * 128;
        u16x2 pv = *(const u16x2*)&pout[prow + l*2];
        float2 xv = *(const float2*)&x[(long)g*128 + l*2];
        float v0 = bf2f(pv[0]) + xv.x;
        float v1 = bf2f(pv[1]) + xv.y;
        float s = v0 + v1, s2 = v0*v0 + v1*v1;
        #pragma unroll
        for (int o = 32; o; o >>= 1) { s += __shfl_xor(s, o); s2 += __shfl_xor(s2, o); }
        float mean = s * (1.f/128.f), var = s2 * (1.f/128.f) - mean*mean;
        float rstd = rsqrtf(var + 1e-5f);
        float y0 = (v0 - mean)*rstd*w2[l*2]   + b2n[l*2];
        float y1 = (v1 - mean)*rstd*w2[l*2+1] + b2n[l*2+1];
        u16x2 xo; xo[0] = f2bf(v0); xo[1] = f2bf(v1);
        *(u16x2*)&lx1[row*136 + l*2] = xo;
        u16x2 ho; ho[0] = f2bf(y0); ho[1] = f2bf(y1);
        *(u16x2*)&lh[row*136 + l*2] = ho;
    }
    __syncthreads();
    // ---- mlp body (r4) ----
    f32x4 oacc[4][2] = {};                   // out cols wv*32 + nt*16 + lr
    for (int ch = 0; ch < 8; ch++) {
        u16* lc = lhc[ch & 1];
        int un0 = ch*64 + wv*16;
        bf16x8 bfr[4];
        #pragma unroll
        for (int kk = 0; kk < 4; kk++)
            bfr[kk] = ld_frag(&fc1T[(un0 + lr)*128 + kk*32 + lk]);
        float bv = b1[un0 + lr];
        #pragma unroll
        for (int mt = 0; mt < 4; mt++) {
            f32x4 acc = {0.f, 0.f, 0.f, 0.f};
            #pragma unroll
            for (int kk = 0; kk < 4; kk++) {
                bf16x8 a = ld_frag(&lh[(mt*16 + lr)*136 + kk*32 + lk]);
                acc = __builtin_amdgcn_mfma_f32_16x16x32_bf16(a, bfr[kk], acc, 0, 0, 0);
            }
            #pragma unroll
            for (int r = 0; r < 4; r++) {
                float v = acc[r] + bv;
                v = v / (1.f + __expf(-v));
                lc[(mt*16 + lg*4 + r)*72 + wv*16 + lr] = f2bf(v);
            }
        }
        __syncthreads();                     // chunk ready; also protects buf reuse
        #pragma unroll
        for (int nt = 0; nt < 2; nt++) {
            int col = wv*32 + nt*16 + lr;
            bf16x8 b0 = ld_frag(&fc2T[(long)col*512 + ch*64 + lk]);
            bf16x8 b1f = ld_frag(&fc2T[(long)col*512 + ch*64 + 32 + lk]);
            #pragma unroll
            for (int mt = 0; mt < 4; mt++) {
                bf16x8 a0 = ld_frag(&lc[(mt*16 + lr)*72 + lk]);
                bf16x8 a1 = ld_frag(&lc[(mt*16 + lr)*72 + 32 + lk]);
                oacc[mt][nt] = __builtin_amdgcn_mfma_f32_16x16x32_bf16(a0, b0, oacc[mt][nt], 0, 0, 0);
                oacc[mt][nt] = __builtin_amdgcn_mfma_f32_16x16x32_bf16(a1, b1f, oacc[mt][nt], 0, 0, 0);
            }
        }
    }
    // epilogue: += b2 + x1(LDS), write fp32
    #pragma unroll
    for (int nt = 0; nt < 2; nt++) {
        int col = wv*32 + nt*16 + lr;
        float bv = b2[col];
        #pragma unroll
        for (int mt = 0; mt < 4; mt++) {
            #pragma unroll
            for (int r = 0; r < 4; r++) {
                int row = mt*16 + lg*4 + r;
                out[(long)(m0 + row)*128 + col] =
                    oacc[mt][nt][r] + bv + bf2f(lx1[row*136 + col]);
            }
        }
    }
}

extern "C" void kernel_launch(void* const* d_in, const int* in_sizes, int n_in,
                              void* d_out, int out_size, void* d_ws, size_t ws_size,
                              hipStream_t stream)
{
    const float* x      = (const float*)d_in[0];
    const float* n1w    = (const float*)d_in[1];
    const float* n1b    = (const float*)d_in[2];
    const float* qkv_w  = (const float*)d_in[3];
    const float* qkv_b  = (const float*)d_in[4];
    const float* proj_w = (const float*)d_in[5];
    const float* proj_b = (const float*)d_in[6];
    const float* n2w    = (const float*)d_in[7];
    const float* n2b    = (const float*)d_in[8];
    const float* fc1_w  = (const float*)d_in[9];
    const float* fc1_b  = (const float*)d_in[10];
    const float* fc2_w  = (const float*)d_in[11];
    const float* fc2_b  = (const float*)d_in[12];
    float* out = (float*)d_out;

    u16* ws16  = (u16*)d_ws;
    u16* xw    = ws16;                        // 12,845,056 u16 (ln1 out -> attn_out in place)
    u16* qkv   = xw + 12845056;               // 38,535,168 u16 (qkv -> proj_out)
    u16* qkvT  = qkv + 38535168;              // 49,152
    u16* projT = qkvT + 49152;                // 16,384
    u16* fc1T  = projT + 16384;               // 65,536
    u16* fc2T  = fc1T + 65536;                // 65,536

    k_wT<<<256, 256, 0, stream>>>(qkv_w, proj_w, fc1_w, fc2_w, qkvT, projT, fc1T, fc2T);
    k_ln1_part<<<25088, 256, 0, stream>>>(x, n1w, n1b, xw);
    dim3 gq(784, 3);
    k_gemm128<<<gq, 256, 0, stream>>>(xw, qkvT, qkv_b, qkv, 384);
    dim3 ga(1024, 4);
    k_attn<<<ga, 256, 0, stream>>>(qkv, xw);                        // attn_out -> xw region
    dim3 gp(784, 1);
    k_gemm128<<<gp, 256, 0, stream>>>(xw, projT, proj_b, qkv, 128); // proj_out -> qkv region
    k_mlp2<<<1568, 256, 0, stream>>>(qkv /*pout*/, x, n2w, n2b,
                                     fc1T, fc1_b, fc2T, fc2_b, out);
}

// Round 9
// 199.655 us; speedup vs baseline: 1.5098x; 1.0967x over previous
//
#include <hip/hip_runtime.h>

typedef unsigned short u16;
typedef unsigned int u32;
typedef __bf16 bf16x8 __attribute__((ext_vector_type(8)));
typedef float f32x4 __attribute__((ext_vector_type(4)));
typedef u16 u16x8 __attribute__((ext_vector_type(8)));
typedef u16 u16x2 __attribute__((ext_vector_type(2)));

__device__ __forceinline__ float bf2f(u16 u) {
    union { u32 u; float f; } c; c.u = ((u32)u) << 16; return c.f;
}
__device__ __forceinline__ u16 f2bf(float f) {
    union { float f; u32 u; } c; c.f = f;
    u32 r = c.u + 0x7fffu + ((c.u >> 16) & 1u);
    return (u16)(r >> 16);
}
__device__ __forceinline__ bf16x8 ld_frag(const u16* p) {
    return *reinterpret_cast<const bf16x8*>(p);
}

// ---------------- K0: transpose weights to [N][K] (K-contiguous), fp32 -> bf16 ----------------
__global__ __launch_bounds__(256) void k_wT(
    const float* __restrict__ qkv_w, const float* __restrict__ proj_w,
    const float* __restrict__ fc1_w, const float* __restrict__ fc2_w,
    u16* __restrict__ qkvT, u16* __restrict__ projT,
    u16* __restrict__ fc1T, u16* __restrict__ fc2T)
{
    int t = blockIdx.x * 256 + threadIdx.x;          // < 65536
    if (t < 49152) { int k = t / 384, n = t % 384; qkvT[n*128 + k] = f2bf(qkv_w[t]); }
    if (t < 16384) { int k = t / 128, n = t % 128; projT[n*128 + k] = f2bf(proj_w[t]); }
    if (t < 65536) { int k = t / 512, n = t % 512; fc1T[n*128 + k] = f2bf(fc1_w[t]); }
    if (t < 65536) { int k = t / 128, n = t % 128; fc2T[n*512 + k] = f2bf(fc2_w[t]); }
}

// ---------------- K1: LN1 + cyclic shift + window partition (fp32 in, bf16 out) ----------------
__global__ __launch_bounds__(256) void k_ln1_part(
    const float* __restrict__ x, const float* __restrict__ w, const float* __restrict__ b,
    u16* __restrict__ xw)
{
    int wv = threadIdx.x >> 6, l = threadIdx.x & 63;
    int g = blockIdx.x * 4 + wv;                      // < 100352
    int wi = g / 98, n = g % 98;
    int iw = wi & 7, ih = (wi >> 3) & 7, id = (wi >> 6) & 3, bb = wi >> 8;
    int tw = n % 7, tt = n / 7, th = tt % 7, td = tt / 7;
    int d  = (id * 2 + td + 1) & 7;
    int hh = ih * 7 + th + 3; if (hh >= 56) hh -= 56;
    int ww = iw * 7 + tw + 3; if (ww >= 56) ww -= 56;
    long src = ((((long)bb * 8 + d) * 56 + hh) * 56 + ww) * 128;
    float2 v = *(const float2*)(x + src + l * 2);
    float f0 = v.x, f1 = v.y;
    float s = f0 + f1, s2 = f0*f0 + f1*f1;
    #pragma unroll
    for (int o = 32; o; o >>= 1) { s += __shfl_xor(s, o); s2 += __shfl_xor(s2, o); }
    float mean = s * (1.f/128.f);
    float var  = s2 * (1.f/128.f) - mean*mean;
    float rstd = rsqrtf(var + 1e-5f);
    float y0 = (f0 - mean) * rstd * w[l*2]   + b[l*2];
    float y1 = (f1 - mean) * rstd * w[l*2+1] + b[l*2+1];
    u16x2 o2; o2[0] = f2bf(y0); o2[1] = f2bf(y1);
    *(u16x2*)(xw + (long)g * 128 + l * 2) = o2;
}

// ---------------- K2/K4: GEMM  C[M,N] = A[M,128] @ BT[N,128]^T + bias ----------------
__global__ __launch_bounds__(256) void k_gemm128(
    const u16* __restrict__ A, const u16* __restrict__ BT,
    const float* __restrict__ bias, u16* __restrict__ out, int ldo)
{
    __shared__ __align__(16) u16 la[128*136];
    __shared__ __align__(16) u16 lb[128*136];
    int m0 = blockIdx.x * 128, n0 = blockIdx.y * 128;
    int t = threadIdx.x;
    #pragma unroll
    for (int i = 0; i < 8; i++) {
        int u = t + i * 256;
        int r = u >> 4, c = u & 15;
        *(u16x8*)&la[r*136 + c*8] = *(const u16x8*)&A [(long)(m0 + r)*128 + c*8];
        *(u16x8*)&lb[r*136 + c*8] = *(const u16x8*)&BT[(long)(n0 + r)*128 + c*8];
    }
    __syncthreads();
    int wv = t >> 6, l = t & 63;
    int wm = (wv & 1) * 64, wn = (wv >> 1) * 64;
    int lr = l & 15, lk = (l >> 4) * 8;
    f32x4 acc[4][4] = {};
    #pragma unroll
    for (int kk = 0; kk < 4; kk++) {
        bf16x8 af[4], bfr[4];
        #pragma unroll
        for (int mi = 0; mi < 4; mi++) af[mi]  = ld_frag(&la[(wm + mi*16 + lr)*136 + kk*32 + lk]);
        #pragma unroll
        for (int ni = 0; ni < 4; ni++) bfr[ni] = ld_frag(&lb[(wn + ni*16 + lr)*136 + kk*32 + lk]);
        #pragma unroll
        for (int mi = 0; mi < 4; mi++)
            #pragma unroll
            for (int ni = 0; ni < 4; ni++)
                acc[mi][ni] = __builtin_amdgcn_mfma_f32_16x16x32_bf16(af[mi], bfr[ni], acc[mi][ni], 0, 0, 0);
    }
    int rb = (l >> 4) * 4;
    #pragma unroll
    for (int mi = 0; mi < 4; mi++)
        #pragma unroll
        for (int ni = 0; ni < 4; ni++) {
            int col = n0 + wn + ni*16 + lr;
            float bv = bias[col];
            #pragma unroll
            for (int r = 0; r < 4; r++) {
                int row = m0 + wm + mi*16 + rb + r;
                out[(long)row*ldo + col] = f2bf(acc[mi][ni][r] + bv);
            }
        }
}

// ---------------- K3: attention per (window, head) — register-resident scores (r3) ----------------
__global__ __launch_bounds__(256) void k_attn(
    const u16* __restrict__ qkv, u16* __restrict__ attn_out)
{
    __shared__ __align__(16) u16 lq[128*40];     // [row][k]  (rows >=98 zero)
    __shared__ __align__(16) u16 lk[128*40];     // [row][k]
    __shared__ __align__(16) u16 lvt[32*136];    // [ch][key] (keys >=98 zero)
    __shared__ __align__(16) u16 lp[4][16*136];  // per-wave P tile [row][key]
    int wi = blockIdx.x, h = blockIdx.y;
    int t = threadIdx.x;
    int wv = t >> 6, l = t & 63;
    const long base = (long)wi * 98 * 384 + h * 32;
    u16* lpw = lp[wv];
    // zero this wave's P buffer (cols 112..127 must stay zero for PV chunk 3)
    {
        u16x8 z8 = {};
        for (int i = l; i < 272; i += 64) *(u16x8*)&lpw[i*8] = z8;
    }
    // stage q,k (zero-padded rows)
    #pragma unroll
    for (int i = 0; i < 4; i++) {
        int u = t + i * 256;                  // < 1024
        int mat = u >> 9, row = (u >> 2) & 127, ch = u & 3;
        u16x8 v = {};
        if (row < 98) v = *(const u16x8*)&qkv[base + (long)row*384 + mat*128 + ch*8];
        u16* dst = mat ? lk : lq;
        *(u16x8*)&dst[row*40 + ch*8] = v;
    }
    // stage v transposed: lvt[ch][key], keys 98..127 zero
    #pragma unroll
    for (int i = 0; i < 2; i++) {
        int u = t + i * 256;                  // < 512
        int row = u >> 2, ch = u & 3;
        u16x8 v = {};
        if (row < 98) v = *(const u16x8*)&qkv[base + (long)row*384 + 256 + ch*8];
        #pragma unroll
        for (int j = 0; j < 8; j++) lvt[(ch*8 + j)*136 + row] = v[j];
    }
    __syncthreads();
    int lr = l & 15, lg = l >> 4, lkk = lg * 8;
    const float scale = 0.17677669529663687f;
    for (int rt = wv; rt < 7; rt += 4) {
        bf16x8 qa = ld_frag(&lq[(rt*16 + lr)*40 + lkk]);
        f32x4 s[7];
        #pragma unroll
        for (int ct = 0; ct < 7; ct++) {
            bf16x8 kb = ld_frag(&lk[(ct*16 + lr)*40 + lkk]);
            f32x4 zz = {0.f, 0.f, 0.f, 0.f};
            s[ct] = __builtin_amdgcn_mfma_f32_16x16x32_bf16(qa, kb, zz, 0, 0, 0);
        }
        #pragma unroll
        for (int ct = 0; ct < 7; ct++) {
            bool valid = (ct < 6) || (lr < 2);
            #pragma unroll
            for (int r = 0; r < 4; r++)
                s[ct][r] = valid ? s[ct][r] * scale : -1e30f;
        }
        f32x4 mx;
        #pragma unroll
        for (int r = 0; r < 4; r++) {
            float m = s[0][r];
            #pragma unroll
            for (int ct = 1; ct < 7; ct++) m = fmaxf(m, s[ct][r]);
            #pragma unroll
            for (int o = 1; o < 16; o <<= 1) m = fmaxf(m, __shfl_xor(m, o));
            mx[r] = m;
        }
        f32x4 sum = {0.f, 0.f, 0.f, 0.f};
        #pragma unroll
        for (int ct = 0; ct < 7; ct++)
            #pragma unroll
            for (int r = 0; r < 4; r++) {
                s[ct][r] = __expf(s[ct][r] - mx[r]);
                sum[r] += s[ct][r];
            }
        #pragma unroll
        for (int r = 0; r < 4; r++) {
            float ss = sum[r];
            #pragma unroll
            for (int o = 1; o < 16; o <<= 1) ss += __shfl_xor(ss, o);
            sum[r] = 1.f / ss;
        }
        #pragma unroll
        for (int ct = 0; ct < 7; ct++)
            #pragma unroll
            for (int r = 0; r < 4; r++)
                lpw[(lg*4 + r)*136 + ct*16 + lr] = f2bf(s[ct][r] * sum[r]);
        #pragma unroll
        for (int ni = 0; ni < 2; ni++) {
            f32x4 acc = {0.f, 0.f, 0.f, 0.f};
            #pragma unroll
            for (int kk = 0; kk < 4; kk++) {
                bf16x8 pa = ld_frag(&lpw[lr*136 + kk*32 + lkk]);
                bf16x8 vb = ld_frag(&lvt[(ni*16 + lr)*136 + kk*32 + lkk]);
                acc = __builtin_amdgcn_mfma_f32_16x16x32_bf16(pa, vb, acc, 0, 0, 0);
            }
            #pragma unroll
            for (int r = 0; r < 4; r++) {
                int row = rt*16 + lg*4 + r;
                if (row < 98)
                    attn_out[((long)wi*98 + row)*128 + h*32 + ni*16 + lr] = f2bf(acc[r]);
            }
        }
    }
}

// ---------------- K6: fused res+LN2+MLP: out = x1 + fc2(silu(fc1(LN2(x1)))),
//                  x1 = window_reverse(proj_out) + x.
// Staging: 16 lanes/row x 8ch, 4 rows/iter (parallel). Fast silu (__fdividef).
// lhc writes XOR-swizzled (row&8)<<2 to kill 4-way write conflicts.
__global__ __launch_bounds__(256, 3) void k_mlp2(
    const u16* __restrict__ pout, const float* __restrict__ x,
    const float* __restrict__ w2, const float* __restrict__ b2n,
    const u16* __restrict__ fc1T, const float* __restrict__ b1,
    const u16* __restrict__ fc2T, const float* __restrict__ b2,
    float* __restrict__ out)
{
    __shared__ __align__(16) u16 lx1[64*136];      // x1 (bf16) for epilogue
    __shared__ __align__(16) u16 lh [64*136];      // h2 = LN2(x1) (bf16)
    __shared__ __align__(16) u16 lhc[2][64*72];    // hidden chunk, double-buffered, swizzled
    int m0 = blockIdx.x * 64;
    int t = threadIdx.x;
    int wv = t >> 6, l = t & 63;
    int lr = l & 15, lg = l >> 4, lk = lg * 8;
    // ---- staging: 4 iterations; each 16-lane group (lg) handles one row, 8 ch/lane ----
    {
        float4 w2a = *(const float4*)&w2 [lr*8];
        float4 w2b = *(const float4*)&w2 [lr*8 + 4];
        float4 b2a = *(const float4*)&b2n[lr*8];
        float4 b2b = *(const float4*)&b2n[lr*8 + 4];
        float w2v[8] = {w2a.x,w2a.y,w2a.z,w2a.w,w2b.x,w2b.y,w2b.z,w2b.w};
        float b2v[8] = {b2a.x,b2a.y,b2a.z,b2a.w,b2b.x,b2b.y,b2b.z,b2b.w};
        for (int it = 0; it < 4; it++) {
            int row = wv*16 + it*4 + lg;
            int g = m0 + row;                       // natural token id
            int ww = g % 56; int t1 = g / 56;
            int hh = t1 % 56; int t2 = t1 / 56;
            int d = t2 & 7, bb = t2 >> 3;
            int d2 = (d + 7) & 7;
            int hs = hh - 3; if (hs < 0) hs += 56;
            int ws_ = ww - 3; if (ws_ < 0) ws_ += 56;
            int id = d2 >> 1, td = d2 & 1;
            int ih = hs / 7, th = hs % 7;
            int iw = ws_ / 7, tw = ws_ % 7;
            int wi = ((bb*4 + id)*8 + ih)*8 + iw;
            int n  = (td*7 + th)*7 + tw;
            long prow = ((long)wi*98 + n) * 128;
            u16x8 pv = *(const u16x8*)&pout[prow + lr*8];
            float4 xa = *(const float4*)&x[(long)g*128 + lr*8];
            float4 xb = *(const float4*)&x[(long)g*128 + lr*8 + 4];
            float v[8];
            v[0] = bf2f(pv[0]) + xa.x; v[1] = bf2f(pv[1]) + xa.y;
            v[2] = bf2f(pv[2]) + xa.z; v[3] = bf2f(pv[3]) + xa.w;
            v[4] = bf2f(pv[4]) + xb.x; v[5] = bf2f(pv[5]) + xb.y;
            v[6] = bf2f(pv[6]) + xb.z; v[7] = bf2f(pv[7]) + xb.w;
            float s = 0.f, s2 = 0.f;
            #pragma unroll
            for (int j = 0; j < 8; j++) { s += v[j]; s2 += v[j]*v[j]; }
            #pragma unroll
            for (int o = 1; o < 16; o <<= 1) { s += __shfl_xor(s, o); s2 += __shfl_xor(s2, o); }
            float mean = s * (1.f/128.f), var = s2 * (1.f/128.f) - mean*mean;
            float rstd = rsqrtf(var + 1e-5f);
            u16x8 xo, ho;
            #pragma unroll
            for (int j = 0; j < 8; j++) {
                xo[j] = f2bf(v[j]);
                ho[j] = f2bf((v[j] - mean)*rstd*w2v[j] + b2v[j]);
            }
            *(u16x8*)&lx1[row*136 + lr*8] = xo;
            *(u16x8*)&lh [row*136 + lr*8] = ho;
        }
    }
    __syncthreads();
    // ---- mlp body ----
    f32x4 oacc[4][2] = {};                   // out cols wv*32 + nt*16 + lr
    for (int ch = 0; ch < 8; ch++) {
        char* lc = (char*)lhc[ch & 1];
        int un0 = ch*64 + wv*16;
        bf16x8 bfr[4];
        #pragma unroll
        for (int kk = 0; kk < 4; kk++)
            bfr[kk] = ld_frag(&fc1T[(un0 + lr)*128 + kk*32 + lk]);
        float bv = b1[un0 + lr];
        #pragma unroll
        for (int mt = 0; mt < 4; mt++) {
            f32x4 acc = {0.f, 0.f, 0.f, 0.f};
            #pragma unroll
            for (int kk = 0; kk < 4; kk++) {
                bf16x8 a = ld_frag(&lh[(mt*16 + lr)*136 + kk*32 + lk]);
                acc = __builtin_amdgcn_mfma_f32_16x16x32_bf16(a, bfr[kk], acc, 0, 0, 0);
            }
            #pragma unroll
            for (int r = 0; r < 4; r++) {
                int row = mt*16 + lg*4 + r;
                float vv = acc[r] + bv;
                vv = __fdividef(vv, 1.f + __expf(-vv));      // fast silu
                int byo = row*144 + ((((wv*16 + lr)*2)) ^ ((row & 8) << 2));
                *(u16*)(lc + byo) = f2bf(vv);
            }
        }
        __syncthreads();                     // chunk ready; also protects buf reuse
        #pragma unroll
        for (int nt = 0; nt < 2; nt++) {
            int col = wv*32 + nt*16 + lr;
            bf16x8 b0 = ld_frag(&fc2T[(long)col*512 + ch*64 + lk]);
            bf16x8 b1f = ld_frag(&fc2T[(long)col*512 + ch*64 + 32 + lk]);
            #pragma unroll
            for (int mt = 0; mt < 4; mt++) {
                int rr = mt*16 + lr;
                int xw_ = (rr & 8) << 2;
                bf16x8 a0 = *(const bf16x8*)(lc + rr*144 + ((lg*16)      ^ xw_));
                bf16x8 a1 = *(const bf16x8*)(lc + rr*144 + ((lg*16 + 64) ^ xw_));
                oacc[mt][nt] = __builtin_amdgcn_mfma_f32_16x16x32_bf16(a0, b0, oacc[mt][nt], 0, 0, 0);
                oacc[mt][nt] = __builtin_amdgcn_mfma_f32_16x16x32_bf16(a1, b1f, oacc[mt][nt], 0, 0, 0);
            }
        }
    }
    // epilogue: += b2 + x1(LDS), write fp32
    #pragma unroll
    for (int nt = 0; nt < 2; nt++) {
        int col = wv*32 + nt*16 + lr;
        float bv = b2[col];
        #pragma unroll
        for (int mt = 0; mt < 4; mt++) {
            #pragma unroll
            for (int r = 0; r < 4; r++) {
                int row = mt*16 + lg*4 + r;
                out[(long)(m0 + row)*128 + col] =
                    oacc[mt][nt][r] + bv + bf2f(lx1[row*136 + col]);
            }
        }
    }
}

extern "C" void kernel_launch(void* const* d_in, const int* in_sizes, int n_in,
                              void* d_out, int out_size, void* d_ws, size_t ws_size,
                              hipStream_t stream)
{
    const float* x      = (const float*)d_in[0];
    const float* n1w    = (const float*)d_in[1];
    const float* n1b    = (const float*)d_in[2];
    const float* qkv_w  = (const float*)d_in[3];
    const float* qkv_b  = (const float*)d_in[4];
    const float* proj_w = (const float*)d_in[5];
    const float* proj_b = (const float*)d_in[6];
    const float* n2w    = (const float*)d_in[7];
    const float* n2b    = (const float*)d_in[8];
    const float* fc1_w  = (const float*)d_in[9];
    const float* fc1_b  = (const float*)d_in[10];
    const float* fc2_w  = (const float*)d_in[11];
    const float* fc2_b  = (const float*)d_in[12];
    float* out = (float*)d_out;

    u16* ws16  = (u16*)d_ws;
    u16* xw    = ws16;                        // 12,845,056 u16 (ln1 out -> attn_out in place)
    u16* qkv   = xw + 12845056;               // 38,535,168 u16 (qkv -> proj_out)
    u16* qkvT  = qkv + 38535168;              // 49,152
    u16* projT = qkvT + 49152;                // 16,384
    u16* fc1T  = projT + 16384;               // 65,536
    u16* fc2T  = fc1T + 65536;                // 65,536

    k_wT<<<256, 256, 0, stream>>>(qkv_w, proj_w, fc1_w, fc2_w, qkvT, projT, fc1T, fc2T);
    k_ln1_part<<<25088, 256, 0, stream>>>(x, n1w, n1b, xw);
    dim3 gq(784, 3);
    k_gemm128<<<gq, 256, 0, stream>>>(xw, qkvT, qkv_b, qkv, 384);
    dim3 ga(1024, 4);
    k_attn<<<ga, 256, 0, stream>>>(qkv, xw);                        // attn_out -> xw region
    dim3 gp(784, 1);
    k_gemm128<<<gp, 256, 0, stream>>>(xw, projT, proj_b, qkv, 128); // proj_out -> qkv region
    k_mlp2<<<1568, 256, 0, stream>>>(qkv /*pout*/, x, n2w, n2b,
                                     fc1T, fc1_b, fc2T, fc2_b, out);
}

// Round 10
// 192.117 us; speedup vs baseline: 1.5690x; 1.0392x over previous
//
#include <hip/hip_runtime.h>

typedef unsigned short u16;
typedef unsigned int u32;
typedef __bf16 bf16x8 __attribute__((ext_vector_type(8)));
typedef float f32x4 __attribute__((ext_vector_type(4)));
typedef u16 u16x8 __attribute__((ext_vector_type(8)));
typedef u16 u16x2 __attribute__((ext_vector_type(2)));

__device__ __forceinline__ float bf2f(u16 u) {
    union { u32 u; float f; } c; c.u = ((u32)u) << 16; return c.f;
}
__device__ __forceinline__ u16 f2bf(float f) {
    union { float f; u32 u; } c; c.f = f;
    u32 r = c.u + 0x7fffu + ((c.u >> 16) & 1u);
    return (u16)(r >> 16);
}
__device__ __forceinline__ u16 f2bfn(float f) {      // native cast -> v_cvt_pk_bf16_f32
    union { __bf16 h; u16 u; } c; c.h = (__bf16)f; return c.u;
}
__device__ __forceinline__ bf16x8 ld_frag(const u16* p) {
    return *reinterpret_cast<const bf16x8*>(p);
}

// ---------------- K0: transpose weights to [N][K] (K-contiguous), fp32 -> bf16 ----------------
__global__ __launch_bounds__(256) void k_wT(
    const float* __restrict__ qkv_w, const float* __restrict__ proj_w,
    const float* __restrict__ fc1_w, const float* __restrict__ fc2_w,
    u16* __restrict__ qkvT, u16* __restrict__ projT,
    u16* __restrict__ fc1T, u16* __restrict__ fc2T)
{
    int t = blockIdx.x * 256 + threadIdx.x;          // < 65536
    if (t < 49152) { int k = t / 384, n = t % 384; qkvT[n*128 + k] = f2bf(qkv_w[t]); }
    if (t < 16384) { int k = t / 128, n = t % 128; projT[n*128 + k] = f2bf(proj_w[t]); }
    if (t < 65536) { int k = t / 512, n = t % 512; fc1T[n*128 + k] = f2bf(fc1_w[t]); }
    if (t < 65536) { int k = t / 128, n = t % 128; fc2T[n*512 + k] = f2bf(fc2_w[t]); }
}

// ---------------- K1: LN1 + cyclic shift + window partition (fp32 in, bf16 out) ----------------
__global__ __launch_bounds__(256) void k_ln1_part(
    const float* __restrict__ x, const float* __restrict__ w, const float* __restrict__ b,
    u16* __restrict__ xw)
{
    int wv = threadIdx.x >> 6, l = threadIdx.x & 63;
    int g = blockIdx.x * 4 + wv;                      // < 100352
    int wi = g / 98, n = g % 98;
    int iw = wi & 7, ih = (wi >> 3) & 7, id = (wi >> 6) & 3, bb = wi >> 8;
    int tw = n % 7, tt = n / 7, th = tt % 7, td = tt / 7;
    int d  = (id * 2 + td + 1) & 7;
    int hh = ih * 7 + th + 3; if (hh >= 56) hh -= 56;
    int ww = iw * 7 + tw + 3; if (ww >= 56) ww -= 56;
    long src = ((((long)bb * 8 + d) * 56 + hh) * 56 + ww) * 128;
    float2 v = *(const float2*)(x + src + l * 2);
    float f0 = v.x, f1 = v.y;
    float s = f0 + f1, s2 = f0*f0 + f1*f1;
    #pragma unroll
    for (int o = 32; o; o >>= 1) { s += __shfl_xor(s, o); s2 += __shfl_xor(s2, o); }
    float mean = s * (1.f/128.f);
    float var  = s2 * (1.f/128.f) - mean*mean;
    float rstd = rsqrtf(var + 1e-5f);
    float y0 = (f0 - mean) * rstd * w[l*2]   + b[l*2];
    float y1 = (f1 - mean) * rstd * w[l*2+1] + b[l*2+1];
    u16x2 o2; o2[0] = f2bf(y0); o2[1] = f2bf(y1);
    *(u16x2*)(xw + (long)g * 128 + l * 2) = o2;
}

// ---------------- K2/K4: GEMM  C[M,N] = A[M,128] @ BT[N,128]^T + bias ----------------
__global__ __launch_bounds__(256) void k_gemm128(
    const u16* __restrict__ A, const u16* __restrict__ BT,
    const float* __restrict__ bias, u16* __restrict__ out, int ldo)
{
    __shared__ __align__(16) u16 la[128*136];
    __shared__ __align__(16) u16 lb[128*136];
    int m0 = blockIdx.x * 128, n0 = blockIdx.y * 128;
    int t = threadIdx.x;
    #pragma unroll
    for (int i = 0; i < 8; i++) {
        int u = t + i * 256;
        int r = u >> 4, c = u & 15;
        *(u16x8*)&la[r*136 + c*8] = *(const u16x8*)&A [(long)(m0 + r)*128 + c*8];
        *(u16x8*)&lb[r*136 + c*8] = *(const u16x8*)&BT[(long)(n0 + r)*128 + c*8];
    }
    __syncthreads();
    int wv = t >> 6, l = t & 63;
    int wm = (wv & 1) * 64, wn = (wv >> 1) * 64;
    int lr = l & 15, lk = (l >> 4) * 8;
    f32x4 acc[4][4] = {};
    #pragma unroll
    for (int kk = 0; kk < 4; kk++) {
        bf16x8 af[4], bfr[4];
        #pragma unroll
        for (int mi = 0; mi < 4; mi++) af[mi]  = ld_frag(&la[(wm + mi*16 + lr)*136 + kk*32 + lk]);
        #pragma unroll
        for (int ni = 0; ni < 4; ni++) bfr[ni] = ld_frag(&lb[(wn + ni*16 + lr)*136 + kk*32 + lk]);
        #pragma unroll
        for (int mi = 0; mi < 4; mi++)
            #pragma unroll
            for (int ni = 0; ni < 4; ni++)
                acc[mi][ni] = __builtin_amdgcn_mfma_f32_16x16x32_bf16(af[mi], bfr[ni], acc[mi][ni], 0, 0, 0);
    }
    int rb = (l >> 4) * 4;
    #pragma unroll
    for (int mi = 0; mi < 4; mi++)
        #pragma unroll
        for (int ni = 0; ni < 4; ni++) {
            int col = n0 + wn + ni*16 + lr;
            float bv = bias[col];
            #pragma unroll
            for (int r = 0; r < 4; r++) {
                int row = m0 + wm + mi*16 + rb + r;
                out[(long)row*ldo + col] = f2bf(acc[mi][ni][r] + bv);
            }
        }
}

// ---------------- K3: attention per (window, head) — register-resident scores (r3) ----------------
__global__ __launch_bounds__(256) void k_attn(
    const u16* __restrict__ qkv, u16* __restrict__ attn_out)
{
    __shared__ __align__(16) u16 lq[128*40];     // [row][k]  (rows >=98 zero)
    __shared__ __align__(16) u16 lk[128*40];     // [row][k]
    __shared__ __align__(16) u16 lvt[32*136];    // [ch][key] (keys >=98 zero)
    __shared__ __align__(16) u16 lp[4][16*136];  // per-wave P tile [row][key]
    int wi = blockIdx.x, h = blockIdx.y;
    int t = threadIdx.x;
    int wv = t >> 6, l = t & 63;
    const long base = (long)wi * 98 * 384 + h * 32;
    u16* lpw = lp[wv];
    // zero this wave's P buffer (cols 112..127 must stay zero for PV chunk 3)
    {
        u16x8 z8 = {};
        for (int i = l; i < 272; i += 64) *(u16x8*)&lpw[i*8] = z8;
    }
    // stage q,k (zero-padded rows)
    #pragma unroll
    for (int i = 0; i < 4; i++) {
        int u = t + i * 256;                  // < 1024
        int mat = u >> 9, row = (u >> 2) & 127, ch = u & 3;
        u16x8 v = {};
        if (row < 98) v = *(const u16x8*)&qkv[base + (long)row*384 + mat*128 + ch*8];
        u16* dst = mat ? lk : lq;
        *(u16x8*)&dst[row*40 + ch*8] = v;
    }
    // stage v transposed: lvt[ch][key], keys 98..127 zero
    #pragma unroll
    for (int i = 0; i < 2; i++) {
        int u = t + i * 256;                  // < 512
        int row = u >> 2, ch = u & 3;
        u16x8 v = {};
        if (row < 98) v = *(const u16x8*)&qkv[base + (long)row*384 + 256 + ch*8];
        #pragma unroll
        for (int j = 0; j < 8; j++) lvt[(ch*8 + j)*136 + row] = v[j];
    }
    __syncthreads();
    int lr = l & 15, lg = l >> 4, lkk = lg * 8;
    const float scale = 0.17677669529663687f;
    for (int rt = wv; rt < 7; rt += 4) {
        bf16x8 qa = ld_frag(&lq[(rt*16 + lr)*40 + lkk]);
        f32x4 s[7];
        #pragma unroll
        for (int ct = 0; ct < 7; ct++) {
            bf16x8 kb = ld_frag(&lk[(ct*16 + lr)*40 + lkk]);
            f32x4 zz = {0.f, 0.f, 0.f, 0.f};
            s[ct] = __builtin_amdgcn_mfma_f32_16x16x32_bf16(qa, kb, zz, 0, 0, 0);
        }
        #pragma unroll
        for (int ct = 0; ct < 7; ct++) {
            bool valid = (ct < 6) || (lr < 2);
            #pragma unroll
            for (int r = 0; r < 4; r++)
                s[ct][r] = valid ? s[ct][r] * scale : -1e30f;
        }
        f32x4 mx;
        #pragma unroll
        for (int r = 0; r < 4; r++) {
            float m = s[0][r];
            #pragma unroll
            for (int ct = 1; ct < 7; ct++) m = fmaxf(m, s[ct][r]);
            #pragma unroll
            for (int o = 1; o < 16; o <<= 1) m = fmaxf(m, __shfl_xor(m, o));
            mx[r] = m;
        }
        f32x4 sum = {0.f, 0.f, 0.f, 0.f};
        #pragma unroll
        for (int ct = 0; ct < 7; ct++)
            #pragma unroll
            for (int r = 0; r < 4; r++) {
                s[ct][r] = __expf(s[ct][r] - mx[r]);
                sum[r] += s[ct][r];
            }
        #pragma unroll
        for (int r = 0; r < 4; r++) {
            float ss = sum[r];
            #pragma unroll
            for (int o = 1; o < 16; o <<= 1) ss += __shfl_xor(ss, o);
            sum[r] = 1.f / ss;
        }
        #pragma unroll
        for (int ct = 0; ct < 7; ct++)
            #pragma unroll
            for (int r = 0; r < 4; r++)
                lpw[(lg*4 + r)*136 + ct*16 + lr] = f2bf(s[ct][r] * sum[r]);
        #pragma unroll
        for (int ni = 0; ni < 2; ni++) {
            f32x4 acc = {0.f, 0.f, 0.f, 0.f};
            #pragma unroll
            for (int kk = 0; kk < 4; kk++) {
                bf16x8 pa = ld_frag(&lpw[lr*136 + kk*32 + lkk]);
                bf16x8 vb = ld_frag(&lvt[(ni*16 + lr)*136 + kk*32 + lkk]);
                acc = __builtin_amdgcn_mfma_f32_16x16x32_bf16(pa, vb, acc, 0, 0, 0);
            }
            #pragma unroll
            for (int r = 0; r < 4; r++) {
                int row = rt*16 + lg*4 + r;
                if (row < 98)
                    attn_out[((long)wi*98 + row)*128 + h*32 + ni*16 + lr] = f2bf(acc[r]);
            }
        }
    }
}

// ---------------- K6: fused res+LN2+MLP: out = x1 + fc2(silu(fc1(LN2(x1)))),
//                  x1 = window_reverse(proj_out) + x.
// x1 (bf16) spills to the dead xw region in global (L2-resident roundtrip) instead
// of LDS: 53.2 -> 35.8 KB -> 4 blocks/CU. Native bf16 casts (v_cvt_pk) in hot paths.
__global__ __launch_bounds__(256, 4) void k_mlp2(
    const u16* __restrict__ pout, const float* __restrict__ x,
    const float* __restrict__ w2, const float* __restrict__ b2n,
    const u16* __restrict__ fc1T, const float* __restrict__ b1,
    const u16* __restrict__ fc2T, const float* __restrict__ b2,
    u16* __restrict__ x1g, float* __restrict__ out)
{
    __shared__ __align__(16) u16 lh [64*136];      // h2 = LN2(x1) (bf16)
    __shared__ __align__(16) u16 lhc[2][64*72];    // hidden chunk, double-buffered, swizzled
    int m0 = blockIdx.x * 64;
    int t = threadIdx.x;
    int wv = t >> 6, l = t & 63;
    int lr = l & 15, lg = l >> 4, lk = lg * 8;
    // ---- staging: 4 iterations; each 16-lane group (lg) handles one row, 8 ch/lane ----
    {
        float4 w2a = *(const float4*)&w2 [lr*8];
        float4 w2b = *(const float4*)&w2 [lr*8 + 4];
        float4 b2a = *(const float4*)&b2n[lr*8];
        float4 b2b = *(const float4*)&b2n[lr*8 + 4];
        float w2v[8] = {w2a.x,w2a.y,w2a.z,w2a.w,w2b.x,w2b.y,w2b.z,w2b.w};
        float b2v[8] = {b2a.x,b2a.y,b2a.z,b2a.w,b2b.x,b2b.y,b2b.z,b2b.w};
        for (int it = 0; it < 4; it++) {
            int row = wv*16 + it*4 + lg;
            int g = m0 + row;                       // natural token id
            int ww = g % 56; int t1 = g / 56;
            int hh = t1 % 56; int t2 = t1 / 56;
            int d = t2 & 7, bb = t2 >> 3;
            int d2 = (d + 7) & 7;
            int hs = hh - 3; if (hs < 0) hs += 56;
            int ws_ = ww - 3; if (ws_ < 0) ws_ += 56;
            int id = d2 >> 1, td = d2 & 1;
            int ih = hs / 7, th = hs % 7;
            int iw = ws_ / 7, tw = ws_ % 7;
            int wi = ((bb*4 + id)*8 + ih)*8 + iw;
            int n  = (td*7 + th)*7 + tw;
            long prow = ((long)wi*98 + n) * 128;
            u16x8 pv = *(const u16x8*)&pout[prow + lr*8];
            float4 xa = *(const float4*)&x[(long)g*128 + lr*8];
            float4 xb = *(const float4*)&x[(long)g*128 + lr*8 + 4];
            float v[8];
            v[0] = bf2f(pv[0]) + xa.x; v[1] = bf2f(pv[1]) + xa.y;
            v[2] = bf2f(pv[2]) + xa.z; v[3] = bf2f(pv[3]) + xa.w;
            v[4] = bf2f(pv[4]) + xb.x; v[5] = bf2f(pv[5]) + xb.y;
            v[6] = bf2f(pv[6]) + xb.z; v[7] = bf2f(pv[7]) + xb.w;
            float s = 0.f, s2 = 0.f;
            #pragma unroll
            for (int j = 0; j < 8; j++) { s += v[j]; s2 += v[j]*v[j]; }
            #pragma unroll
            for (int o = 1; o < 16; o <<= 1) { s += __shfl_xor(s, o); s2 += __shfl_xor(s2, o); }
            float mean = s * (1.f/128.f), var = s2 * (1.f/128.f) - mean*mean;
            float rstd = rsqrtf(var + 1e-5f);
            u16x8 xo, ho;
            #pragma unroll
            for (int j = 0; j < 8; j++) {
                xo[j] = f2bfn(v[j]);
                ho[j] = f2bfn((v[j] - mean)*rstd*w2v[j] + b2v[j]);
            }
            *(u16x8*)&x1g[(long)g*128 + lr*8] = xo;    // x1 -> global (L2-resident)
            *(u16x8*)&lh [row*136 + lr*8] = ho;
        }
    }
    __syncthreads();
    // ---- mlp body ----
    f32x4 oacc[4][2] = {};                   // out cols wv*32 + nt*16 + lr
    for (int ch = 0; ch < 8; ch++) {
        char* lc = (char*)lhc[ch & 1];
        int un0 = ch*64 + wv*16;
        bf16x8 bfr[4];
        #pragma unroll
        for (int kk = 0; kk < 4; kk++)
            bfr[kk] = ld_frag(&fc1T[(un0 + lr)*128 + kk*32 + lk]);
        float bv = b1[un0 + lr];
        #pragma unroll
        for (int mt = 0; mt < 4; mt++) {
            f32x4 acc = {0.f, 0.f, 0.f, 0.f};
            #pragma unroll
            for (int kk = 0; kk < 4; kk++) {
                bf16x8 a = ld_frag(&lh[(mt*16 + lr)*136 + kk*32 + lk]);
                acc = __builtin_amdgcn_mfma_f32_16x16x32_bf16(a, bfr[kk], acc, 0, 0, 0);
            }
            #pragma unroll
            for (int r = 0; r < 4; r++) {
                int row = mt*16 + lg*4 + r;
                float vv = acc[r] + bv;
                vv = __fdividef(vv, 1.f + __expf(-vv));      // fast silu
                int byo = row*144 + ((((wv*16 + lr)*2)) ^ ((row & 8) << 2));
                *(u16*)(lc + byo) = f2bfn(vv);
            }
        }
        __syncthreads();                     // chunk ready; also protects buf reuse
        #pragma unroll
        for (int nt = 0; nt < 2; nt++) {
            int col = wv*32 + nt*16 + lr;
            bf16x8 b0 = ld_frag(&fc2T[(long)col*512 + ch*64 + lk]);
            bf16x8 b1f = ld_frag(&fc2T[(long)col*512 + ch*64 + 32 + lk]);
            #pragma unroll
            for (int mt = 0; mt < 4; mt++) {
                int rr = mt*16 + lr;
                int xw_ = (rr & 8) << 2;
                bf16x8 a0 = *(const bf16x8*)(lc + rr*144 + ((lg*16)      ^ xw_));
                bf16x8 a1 = *(const bf16x8*)(lc + rr*144 + ((lg*16 + 64) ^ xw_));
                oacc[mt][nt] = __builtin_amdgcn_mfma_f32_16x16x32_bf16(a0, b0, oacc[mt][nt], 0, 0, 0);
                oacc[mt][nt] = __builtin_amdgcn_mfma_f32_16x16x32_bf16(a1, b1f, oacc[mt][nt], 0, 0, 0);
            }
        }
    }
    // epilogue: += b2 + x1(global, L2-hot), write fp32
    #pragma unroll
    for (int nt = 0; nt < 2; nt++) {
        int col = wv*32 + nt*16 + lr;
        float bv = b2[col];
        #pragma unroll
        for (int mt = 0; mt < 4; mt++) {
            #pragma unroll
            for (int r = 0; r < 4; r++) {
                int row = mt*16 + lg*4 + r;
                out[(long)(m0 + row)*128 + col] =
                    oacc[mt][nt][r] + bv + bf2f(x1g[(long)(m0 + row)*128 + col]);
            }
        }
    }
}

extern "C" void kernel_launch(void* const* d_in, const int* in_sizes, int n_in,
                              void* d_out, int out_size, void* d_ws, size_t ws_size,
                              hipStream_t stream)
{
    const float* x      = (const float*)d_in[0];
    const float* n1w    = (const float*)d_in[1];
    const float* n1b    = (const float*)d_in[2];
    const float* qkv_w  = (const float*)d_in[3];
    const float* qkv_b  = (const float*)d_in[4];
    const float* proj_w = (const float*)d_in[5];
    const float* proj_b = (const float*)d_in[6];
    const float* n2w    = (const float*)d_in[7];
    const float* n2b    = (const float*)d_in[8];
    const float* fc1_w  = (const float*)d_in[9];
    const float* fc1_b  = (const float*)d_in[10];
    const float* fc2_w  = (const float*)d_in[11];
    const float* fc2_b  = (const float*)d_in[12];
    float* out = (float*)d_out;

    u16* ws16  = (u16*)d_ws;
    u16* xw    = ws16;                        // 12,845,056 u16 (ln1 out -> attn_out -> x1 spill)
    u16* qkv   = xw + 12845056;               // 38,535,168 u16 (qkv -> proj_out)
    u16* qkvT  = qkv + 38535168;              // 49,152
    u16* projT = qkvT + 49152;                // 16,384
    u16* fc1T  = projT + 16384;               // 65,536
    u16* fc2T  = fc1T + 65536;                // 65,536

    k_wT<<<256, 256, 0, stream>>>(qkv_w, proj_w, fc1_w, fc2_w, qkvT, projT, fc1T, fc2T);
    k_ln1_part<<<25088, 256, 0, stream>>>(x, n1w, n1b, xw);
    dim3 gq(784, 3);
    k_gemm128<<<gq, 256, 0, stream>>>(xw, qkvT, qkv_b, qkv, 384);
    dim3 ga(1024, 4);
    k_attn<<<ga, 256, 0, stream>>>(qkv, xw);                        // attn_out -> xw region
    dim3 gp(784, 1);
    k_gemm128<<<gp, 256, 0, stream>>>(xw, projT, proj_b, qkv, 128); // proj_out -> qkv region
    k_mlp2<<<1568, 256, 0, stream>>>(qkv /*pout*/, x, n2w, n2b,
                                     fc1T, fc1_b, fc2T, fc2_b,
                                     xw /*x1 spill (attn_out is dead)*/, out);
}